// Round 4
// baseline (4570.262 us; speedup 1.0000x reference)
//
#include <hip/hip_runtime.h>
#include <hip/hip_bf16.h>
#include <stdint.h>

typedef __hip_bfloat16 bf16;

#define EPSBN 1e-5f
#define CHUNK 14080      // edges per k_bucket WG (56320 B LDS staging)
#define BSH   9          // 512-node buckets
#define BCAP  22528      // per-bucket padded capacity (E[~19930] + >5 sigma)
#define SENT  0xFFFFFFFFu
#define RSH   15         // src-range shift: 32768 rows = 2 MB of Y per range
#define NRMAX 7          // ceil(200000 / 32768)
#define NSEG  8          // NRMAX + 1

__device__ __forceinline__ float bits2f(unsigned int u) { return __uint_as_float(u); }

__device__ __forceinline__ void atomAddF(float* p, float v) {
#if defined(__HIP_DEVICE_COMPILE__)
    unsafeAtomicAdd(p, v);   // native global_atomic_add_f32 on gfx950
#else
    atomicAdd(p, v);
#endif
}

// ---- per-graph node counts ----
__global__ __launch_bounds__(256) void k_cntg(const int* __restrict__ batch,
                                              int* __restrict__ cntg, int n) {
    int i = blockIdx.x * 256 + threadIdx.x;
    if (i < n) atomicAdd(&cntg[batch[i]], 1);
}

// ======== CSR phase 1: LDS counting-sort per chunk, coalesced padded flush ====
__global__ __launch_bounds__(512) void k_bucket(const int* __restrict__ ei, int E,
                                                int* __restrict__ bcntP,
                                                int* __restrict__ bcntR,
                                                unsigned int* __restrict__ pairT,
                                                int NB) {
    __shared__ unsigned int stage[CHUNK];   // compact, grouped by bucket
    __shared__ int cR[512];                 // real count per bucket
    __shared__ int lbase[512];              // exclusive scan of cR
    __shared__ int gpos[512];               // global reserved base per bucket
    __shared__ int lhead[512];              // placement heads
    int t = threadIdx.x;
    int e0 = blockIdx.x * CHUNK;
    int e1 = e0 + CHUNK; if (e1 > E) e1 = E;
    const int* dst = ei + E;

    cR[t] = 0; lhead[t] = 0;
    __syncthreads();
    for (int e = e0 + t; e < e1; e += 512) atomicAdd(&cR[dst[e] >> BSH], 1);
    __syncthreads();
    int c = cR[t];
    lbase[t] = c;
    __syncthreads();
    for (int off = 1; off < 512; off <<= 1) {
        int u = (t >= off) ? lbase[t - off] : 0;
        __syncthreads();
        lbase[t] += u;
        __syncthreads();
    }
    lbase[t] -= c;                           // exclusive
    if (t < NB && c > 0) {
        int p16 = (c + 15) & ~15;
        gpos[t] = atomicAdd(&bcntP[t], p16);
        atomicAdd(&bcntR[t], c);
    } else {
        gpos[t] = 0;
    }
    __syncthreads();
    for (int e = e0 + t; e < e1; e += 512) {
        int s = ei[e], d = dst[e];
        int b = d >> BSH;
        int pos = atomicAdd(&lhead[b], 1);
        stage[lbase[b] + pos] = (unsigned int)s | ((unsigned int)(d & 511) << 18);
    }
    __syncthreads();
    int wave = t >> 6, lane = t & 63;
    for (int b = wave; b < NB; b += 8) {
        int cc = cR[b];
        if (cc == 0) continue;
        int p16 = (cc + 15) & ~15;
        int lb = lbase[b];
        size_t gb = (size_t)b * BCAP + gpos[b];
        for (int j = lane; j < p16; j += 64) {
            unsigned int v = (j < cc) ? stage[lb + j] : SENT;
            if (gpos[b] + j < BCAP) pairT[gb + j] = v;
        }
    }
}

// ======== phase 2a: scan real bucket totals -> bucket bases ====
__global__ __launch_bounds__(1024) void k_bscan(const int* __restrict__ bcntR,
                                                int* __restrict__ bbase, int NB) {
    __shared__ int s[1024];
    int t = threadIdx.x;
    int c = (t < NB) ? bcntR[t] : 0;
    s[t] = c;
    __syncthreads();
    for (int off = 1; off < 1024; off <<= 1) {
        int u = (t >= off) ? s[t - off] : 0;
        __syncthreads();
        s[t] += u;
        __syncthreads();
    }
    if (t < NB) bbase[t] = s[t] - c;                // exclusive
}

// ======== phase 2b: per-bucket range-major packed-edge build ====
// Bucket b's col segment is laid out range-major; entries stay PACKED
// (src | dstLocal<<18) so the gather needs no per-row metadata at all.
// segS[b*NSEG + r] = absolute start of (bucket b, range r); NSEG-1 = end.
__global__ __launch_bounds__(512) void k_build(const unsigned int* __restrict__ pairT,
                                               const int* __restrict__ bcntP,
                                               const int* __restrict__ bbase,
                                               float* __restrict__ dinv,
                                               int* __restrict__ segS,
                                               unsigned int* __restrict__ colP,
                                               int n, int NR) {
    __shared__ int lcnt2[512 * NRMAX];
    __shared__ int head2[512 * NRMAX];
    __shared__ int stmp[512];
    int b = blockIdx.x, t = threadIdx.x;
    int bn0 = b << BSH;
    int nn = n - bn0; if (nn > 512) nn = 512; if (nn < 0) nn = 0;
    int m = min(bcntP[b], BCAP);
    const unsigned int* P = pairT + (size_t)b * BCAP;
    for (int i = t; i < 512 * NRMAX; i += 512) lcnt2[i] = 0;
    __syncthreads();
    // histogram per (row, src-range)
    for (int i = t; i < m; i += 512) {
        unsigned int v = P[i];
        if (v != SENT)
            atomicAdd(&lcnt2[(v >> 18) * NRMAX + ((v & 0x3FFFFu) >> RSH)], 1);
    }
    __syncthreads();
    // degree -> dinv
    int rowc = 0;
#pragma unroll
    for (int r = 0; r < NRMAX; ++r) rowc += lcnt2[t * NRMAX + r];
    if (t < nn) dinv[bn0 + t] = rsqrtf((float)(rowc + 1));   // + self-loop
    int runbase = bbase[b];            // uniform across threads
    for (int r = 0; r < NR; ++r) {
        if (t == 0) segS[b * NSEG + r] = runbase;
        int c = lcnt2[t * NRMAX + r];
        stmp[t] = c;
        __syncthreads();
        for (int off = 1; off < 512; off <<= 1) {
            int u = (t >= off) ? stmp[t - off] : 0;
            __syncthreads();
            stmp[t] += u;
            __syncthreads();
        }
        head2[t * NRMAX + r] = runbase + stmp[t] - c;
        int tot = stmp[511];
        __syncthreads();                // protect stmp before next-r overwrite
        runbase += tot;
    }
    if (t == 0) segS[b * NSEG + NR] = runbase;
    __syncthreads();
    // placement: packed entries at absolute offsets
    for (int i = t; i < m; i += 512) {
        unsigned int v = P[i];
        if (v != SENT) {
            unsigned int src = v & 0x3FFFFu;
            int pos = atomicAdd(&head2[(v >> 18) * NRMAX + (src >> RSH)], 1);
            colP[pos] = v;
        }
    }
}

// ======== GEMMs (Y = bf16(dinv * (X @ W)), BN affine folded for 32-wide) ====

__global__ __launch_bounds__(256) void k_gemm1(const float* __restrict__ x,
                                               const float* __restrict__ W,
                                               const float* __restrict__ dinv,
                                               bf16* __restrict__ Y, int n) {
    __shared__ float Ws[128 * 32];
    __shared__ float xs[32 * 128];
    int tid = threadIdx.x;
    int base = blockIdx.x * 32;
    for (int i = tid; i < 128 * 32; i += 256) Ws[i] = W[i];
    if (base + 32 <= n) {
        const float4* x4 = (const float4*)(x + (size_t)base * 128);
        for (int i = tid; i < 1024; i += 256) {
            float4 v = x4[i];
            xs[i * 4 + 0] = v.x; xs[i * 4 + 1] = v.y;
            xs[i * 4 + 2] = v.z; xs[i * 4 + 3] = v.w;
        }
    } else {
        for (int i = tid; i < 32 * 128; i += 256) {
            int r = i >> 7, c = i & 127;
            int row = base + r;
            xs[i] = (row < n) ? x[(size_t)row * 128 + c] : 0.f;
        }
    }
    __syncthreads();
    int r0 = tid >> 5, j = tid & 31;
    float a0 = 0.f, a1 = 0.f, a2 = 0.f, a3 = 0.f;
#pragma unroll 8
    for (int k = 0; k < 128; ++k) {
        float w = Ws[k * 32 + j];
        a0 = fmaf(xs[(r0     ) * 128 + k], w, a0);
        a1 = fmaf(xs[(r0 +  8) * 128 + k], w, a1);
        a2 = fmaf(xs[(r0 + 16) * 128 + k], w, a2);
        a3 = fmaf(xs[(r0 + 24) * 128 + k], w, a3);
    }
    int row;
    row = base + r0;      if (row < n) Y[(size_t)row * 32 + j] = __float2bfloat16(a0 * dinv[row]);
    row = base + r0 + 8;  if (row < n) Y[(size_t)row * 32 + j] = __float2bfloat16(a1 * dinv[row]);
    row = base + r0 + 16; if (row < n) Y[(size_t)row * 32 + j] = __float2bfloat16(a2 * dinv[row]);
    row = base + r0 + 24; if (row < n) Y[(size_t)row * 32 + j] = __float2bfloat16(a3 * dinv[row]);
}

__global__ __launch_bounds__(256) void k_gemm32(const float* __restrict__ H,
                                                const float* __restrict__ W,
                                                const float* __restrict__ scale,
                                                const float* __restrict__ shift,
                                                const float* __restrict__ dinv,
                                                bf16* __restrict__ Y, int n) {
    __shared__ float Ws[32 * 32];
    __shared__ float xs[32 * 32];
    int tid = threadIdx.x;
    int base = blockIdx.x * 32;
    for (int i = tid; i < 1024; i += 256) Ws[i] = W[i];
    for (int i = tid; i < 1024; i += 256) {
        int r = i >> 5, k = i & 31;
        int row = base + r;
        xs[i] = (row < n) ? fmaf(H[(size_t)row * 32 + k], scale[k], shift[k]) : 0.f;
    }
    __syncthreads();
    int r0 = tid >> 5, j = tid & 31;
    float a0 = 0.f, a1 = 0.f, a2 = 0.f, a3 = 0.f;
#pragma unroll
    for (int k = 0; k < 32; ++k) {
        float w = Ws[k * 32 + j];
        a0 = fmaf(xs[(r0     ) * 32 + k], w, a0);
        a1 = fmaf(xs[(r0 +  8) * 32 + k], w, a1);
        a2 = fmaf(xs[(r0 + 16) * 32 + k], w, a2);
        a3 = fmaf(xs[(r0 + 24) * 32 + k], w, a3);
    }
    int row;
    row = base + r0;      if (row < n) Y[(size_t)row * 32 + j] = __float2bfloat16(a0 * dinv[row]);
    row = base + r0 + 8;  if (row < n) Y[(size_t)row * 32 + j] = __float2bfloat16(a1 * dinv[row]);
    row = base + r0 + 16; if (row < n) Y[(size_t)row * 32 + j] = __float2bfloat16(a2 * dinv[row]);
    row = base + r0 + 24; if (row < n) Y[(size_t)row * 32 + j] = __float2bfloat16(a3 * dinv[row]);
}

// ======== bucket-resident LDS-accumulate gather ========
// Block b owns rows [b*512, b*512+512): acc[512][32] f32 in LDS (64 KB),
// initialized with the self-loop Y rows. Ranges swept in order; all blocks
// co-resident (2/CU) and barrier-aligned per range -> per-XCD L2 holds the
// rotating 2 MB Y slice. Edge-parallel: 4 lanes/edge (sub = 8-feat quad),
// one colP broadcast + one 64B Y row per edge, 8 LDS float atomics.
// Feature index XOR-swizzled by (row&31): spreads banks AND same-row
// collisions across instrs; all indices compile-time (no scratch).

__global__ __launch_bounds__(512) void k_gather_bn(const int* __restrict__ segS,
                                                   const unsigned int* __restrict__ colP,
                                                   const bf16* __restrict__ Y,
                                                   const float* __restrict__ bias,
                                                   const float* __restrict__ dinv,
                                                   float* __restrict__ H,
                                                   float* __restrict__ stats,
                                                   int n, int NR) {
    __shared__ float acc[512 * 32];   // 64 KB; slot = row*32 + (feat ^ (row&31))
    int b = blockIdx.x, t = threadIdx.x;
    int bn0 = b << BSH;
    int nn = n - bn0; if (nn > 512) nn = 512;
    // self-loop init
    for (int i = t; i < 2048; i += 512) {
        int row = i >> 2, q = i & 3, k = row & 31, q8 = q * 8, p = row * 32;
        uint4 v = make_uint4(0u, 0u, 0u, 0u);
        if (row < nn) v = *(const uint4*)(Y + ((size_t)(bn0 + row)) * 32 + q8);
        acc[p + ((q8 + 0) ^ k)] = bits2f(v.x << 16);
        acc[p + ((q8 + 1) ^ k)] = bits2f(v.x & 0xFFFF0000u);
        acc[p + ((q8 + 2) ^ k)] = bits2f(v.y << 16);
        acc[p + ((q8 + 3) ^ k)] = bits2f(v.y & 0xFFFF0000u);
        acc[p + ((q8 + 4) ^ k)] = bits2f(v.z << 16);
        acc[p + ((q8 + 5) ^ k)] = bits2f(v.z & 0xFFFF0000u);
        acc[p + ((q8 + 6) ^ k)] = bits2f(v.w << 16);
        acc[p + ((q8 + 7) ^ k)] = bits2f(v.w & 0xFFFF0000u);
    }
    __syncthreads();
    int q8 = (t & 3) * 8;
    const int* seg = segS + b * NSEG;
    for (int r = 0; r < NR; ++r) {
        int s1 = seg[r + 1];
        int i = seg[r] + (t >> 2);
        unsigned int v = (i < s1) ? colP[i] : 0u;
        while (i < s1) {
            int inext = i + 128;
            unsigned int vn = (inext < s1) ? colP[inext] : 0u;  // lookahead
            int src = (int)(v & 0x3FFFFu);
            int dl = (int)(v >> 18);
            uint4 y = *(const uint4*)(Y + (size_t)src * 32 + q8);
            int k = dl & 31, p = dl * 32;
            atomicAdd(&acc[p + ((q8 + 0) ^ k)], bits2f(y.x << 16));
            atomicAdd(&acc[p + ((q8 + 1) ^ k)], bits2f(y.x & 0xFFFF0000u));
            atomicAdd(&acc[p + ((q8 + 2) ^ k)], bits2f(y.y << 16));
            atomicAdd(&acc[p + ((q8 + 3) ^ k)], bits2f(y.y & 0xFFFF0000u));
            atomicAdd(&acc[p + ((q8 + 4) ^ k)], bits2f(y.z << 16));
            atomicAdd(&acc[p + ((q8 + 5) ^ k)], bits2f(y.z & 0xFFFF0000u));
            atomicAdd(&acc[p + ((q8 + 6) ^ k)], bits2f(y.w << 16));
            atomicAdd(&acc[p + ((q8 + 7) ^ k)], bits2f(y.w & 0xFFFF0000u));
            i = inext; v = vn;
        }
        __syncthreads();   // keep block's waves range-aligned
    }
    // epilogue: feat-parallel, conflict-free
    int fr = t >> 5, f = t & 31;
    float bs = bias[f];
    float sA = 0.f, sQ = 0.f;
    for (int rr = fr; rr < nn; rr += 16) {
        int row = bn0 + rr;
        float a = acc[rr * 32 + (f ^ (rr & 31))];
        float h = tanhf(fmaf(dinv[row], a, bs));
        H[(size_t)row * 32 + f] = h;
        sA += h; sQ += h * h;
    }
    __syncthreads();                   // acc reads done; reuse head as stats
    if (t < 64) acc[t] = 0.f;
    __syncthreads();
    atomicAdd(&acc[f], sA);
    atomicAdd(&acc[32 + f], sQ);
    __syncthreads();
    if (t < 64) atomAddF(&stats[t], acc[t]);
}

__global__ __launch_bounds__(512) void k_gather_pool(const int* __restrict__ segS,
                                                     const unsigned int* __restrict__ colP,
                                                     const bf16* __restrict__ Y,
                                                     const float* __restrict__ bias,
                                                     const float* __restrict__ dinv,
                                                     const int* __restrict__ batch,
                                                     float* __restrict__ pool,
                                                     int n, int NR) {
    __shared__ float acc[512 * 32];   // 64 KB
    int b = blockIdx.x, t = threadIdx.x;
    int bn0 = b << BSH;
    int nn = n - bn0; if (nn > 512) nn = 512;
    for (int i = t; i < 2048; i += 512) {
        int row = i >> 2, q = i & 3, k = row & 31, q8 = q * 8, p = row * 32;
        uint4 v = make_uint4(0u, 0u, 0u, 0u);
        if (row < nn) v = *(const uint4*)(Y + ((size_t)(bn0 + row)) * 32 + q8);
        acc[p + ((q8 + 0) ^ k)] = bits2f(v.x << 16);
        acc[p + ((q8 + 1) ^ k)] = bits2f(v.x & 0xFFFF0000u);
        acc[p + ((q8 + 2) ^ k)] = bits2f(v.y << 16);
        acc[p + ((q8 + 3) ^ k)] = bits2f(v.y & 0xFFFF0000u);
        acc[p + ((q8 + 4) ^ k)] = bits2f(v.z << 16);
        acc[p + ((q8 + 5) ^ k)] = bits2f(v.z & 0xFFFF0000u);
        acc[p + ((q8 + 6) ^ k)] = bits2f(v.w << 16);
        acc[p + ((q8 + 7) ^ k)] = bits2f(v.w & 0xFFFF0000u);
    }
    __syncthreads();
    int q8 = (t & 3) * 8;
    const int* seg = segS + b * NSEG;
    for (int r = 0; r < NR; ++r) {
        int s1 = seg[r + 1];
        int i = seg[r] + (t >> 2);
        unsigned int v = (i < s1) ? colP[i] : 0u;
        while (i < s1) {
            int inext = i + 128;
            unsigned int vn = (inext < s1) ? colP[inext] : 0u;
            int src = (int)(v & 0x3FFFFu);
            int dl = (int)(v >> 18);
            uint4 y = *(const uint4*)(Y + (size_t)src * 32 + q8);
            int k = dl & 31, p = dl * 32;
            atomicAdd(&acc[p + ((q8 + 0) ^ k)], bits2f(y.x << 16));
            atomicAdd(&acc[p + ((q8 + 1) ^ k)], bits2f(y.x & 0xFFFF0000u));
            atomicAdd(&acc[p + ((q8 + 2) ^ k)], bits2f(y.y << 16));
            atomicAdd(&acc[p + ((q8 + 3) ^ k)], bits2f(y.y & 0xFFFF0000u));
            atomicAdd(&acc[p + ((q8 + 4) ^ k)], bits2f(y.z << 16));
            atomicAdd(&acc[p + ((q8 + 5) ^ k)], bits2f(y.z & 0xFFFF0000u));
            atomicAdd(&acc[p + ((q8 + 6) ^ k)], bits2f(y.w << 16));
            atomicAdd(&acc[p + ((q8 + 7) ^ k)], bits2f(y.w & 0xFFFF0000u));
            i = inext; v = vn;
        }
        __syncthreads();
    }
    int fr = t >> 5, f = t & 31;
    float bs = bias[f];
    for (int rr = fr; rr < nn; rr += 16) {
        int row = bn0 + rr;
        float a = acc[rr * 32 + (f ^ (rr & 31))];
        float h = tanhf(fmaf(dinv[row], a, bs));
        atomAddF(&pool[(size_t)batch[row] * 32 + f], h);
    }
}

// ---- finalize BN -> per-feature affine (scale, shift) ----
__global__ void k_bnfin(const float* __restrict__ stats, const float* __restrict__ g,
                        const float* __restrict__ be, float* __restrict__ scale,
                        float* __restrict__ shift, float invN) {
    int f = threadIdx.x;  // 32 threads
    float mu = stats[f] * invN;
    float var = stats[32 + f] * invN - mu * mu;
    float inv = rsqrtf(var + EPSBN);
    float sc = g[f] * inv;
    scale[f] = sc;
    shift[f] = be[f] - mu * sc;
}

// ---- head: out[g] = (pool[g]/cnt[g]) @ Wc + bc ----
__global__ __launch_bounds__(256) void k_final(const float* __restrict__ pool,
                                               const int* __restrict__ cntg,
                                               const float* __restrict__ Wc,
                                               const float* __restrict__ bc,
                                               float* __restrict__ out, int G) {
    int g = blockIdx.x * 256 + threadIdx.x;
    if (g >= G) return;
    float inv = 1.f / (float)max(cntg[g], 1);
    float acc = bc[0];
#pragma unroll
    for (int f = 0; f < 32; ++f) acc = fmaf(pool[(size_t)g * 32 + f] * inv, Wc[f], acc);
    out[g] = acc;
}

extern "C" void kernel_launch(void* const* d_in, const int* in_sizes, int n_in,
                              void* d_out, int out_size, void* d_ws, size_t ws_size,
                              hipStream_t stream) {
    const float* x    = (const float*)d_in[0];
    const int*   ei   = (const int*)d_in[1];
    const int*   batch= (const int*)d_in[2];
    const float* W1   = (const float*)d_in[3];
    const float* b1   = (const float*)d_in[4];
    const float* g1   = (const float*)d_in[5];
    const float* be1  = (const float*)d_in[6];
    const float* W2   = (const float*)d_in[7];
    const float* b2   = (const float*)d_in[8];
    const float* g2   = (const float*)d_in[9];
    const float* be2  = (const float*)d_in[10];
    const float* W3   = (const float*)d_in[11];
    const float* b3   = (const float*)d_in[12];
    // d_in[13], d_in[14] = g3, be3 (unused by reference)
    const float* Wc   = (const float*)d_in[15];
    const float* bc   = (const float*)d_in[16];
    float* out = (float*)d_out;

    const int n = in_sizes[0] / 128;   // 200000
    const int E = in_sizes[1] / 2;     // 6400000
    const int G = out_size;            // 2048
    const int NB = (n + 511) >> 9;     // 391 buckets of 512 nodes
    const int NR = (n + (1 << RSH) - 1) >> RSH;   // 7 src ranges

    char* p = (char*)d_ws;
    auto alloc = [&p](size_t bytes) -> char* {
        uintptr_t q = ((uintptr_t)p + 255) & ~(uintptr_t)255;
        p = (char*)(q + bytes);
        return (char*)q;
    };
    // zero-initialized region first (contiguous from d_ws start)
    int*   cntg  = (int*)alloc((size_t)G * 4);
    float* stats = (float*)alloc(128 * 4);            // BN1: [0,64), BN2: [64,128)
    float* pool  = (float*)alloc((size_t)G * 32 * 4);
    int*   bcntP = (int*)alloc((size_t)NB * 4);       // padded reservations
    int*   bcntR = (int*)alloc((size_t)NB * 4);       // real counts
    size_t zero_bytes = (size_t)(p - (char*)d_ws);
    float* dinv   = (float*)alloc((size_t)n * 4);
    float* scale1 = (float*)alloc(32 * 4);
    float* shift1 = (float*)alloc(32 * 4);
    float* scale2 = (float*)alloc(32 * 4);
    float* shift2 = (float*)alloc(32 * 4);
    int*   bbase  = (int*)alloc((size_t)(NB + 1) * 4);
    int*   segS   = (int*)alloc((size_t)NB * NSEG * 4);          // 12.5 KB
    unsigned int* pairT = (unsigned int*)alloc((size_t)NB * BCAP * 4);  // ~35 MB
    unsigned int* colP  = (unsigned int*)alloc((size_t)E * 4);   // packed edges
    bf16*  bufY   = (bf16*)alloc((size_t)n * 32 * 2);
    float* bufH   = (float*)alloc((size_t)n * 32 * 4);

    hipMemsetAsync(d_ws, 0, zero_bytes, stream);

    int gN    = (n + 255) / 256;
    int gR32  = (n + 31) / 32;
    int gBuk  = (E + CHUNK - 1) / CHUNK;
    float invN = 1.0f / (float)n;

    // ---- build CSR (once; shared by all 3 layers) ----
    k_cntg  <<<gN, 256, 0, stream>>>(batch, cntg, n);
    k_bucket<<<gBuk, 512, 0, stream>>>(ei, E, bcntP, bcntR, pairT, NB);
    k_bscan <<<1, 1024, 0, stream>>>(bcntR, bbase, NB);
    k_build <<<NB, 512, 0, stream>>>(pairT, bcntP, bbase, dinv, segS, colP, n, NR);

    // ---- layer 1 ----
    k_gemm1<<<gR32, 256, 0, stream>>>(x, W1, dinv, bufY, n);
    k_gather_bn<<<NB, 512, 0, stream>>>(segS, colP, bufY, b1, dinv, bufH, stats, n, NR);
    k_bnfin<<<1, 32, 0, stream>>>(stats, g1, be1, scale1, shift1, invN);

    // ---- layer 2 ----
    k_gemm32<<<gR32, 256, 0, stream>>>(bufH, W2, scale1, shift1, dinv, bufY, n);
    k_gather_bn<<<NB, 512, 0, stream>>>(segS, colP, bufY, b2, dinv, bufH, stats + 64, n, NR);
    k_bnfin<<<1, 32, 0, stream>>>(stats + 64, g2, be2, scale2, shift2, invN);

    // ---- layer 3 (tanh fused into pooling; no BN) ----
    k_gemm32<<<gR32, 256, 0, stream>>>(bufH, W3, scale2, shift2, dinv, bufY, n);
    k_gather_pool<<<NB, 512, 0, stream>>>(segS, colP, bufY, b3, dinv, batch, pool, n, NR);

    // ---- head ----
    k_final<<<(G + 255) / 256, 256, 0, stream>>>(pool, cntg, Wc, bc, out, G);
}

// Round 6
// 3667.368 us; speedup vs baseline: 1.2462x; 1.2462x over previous
//
// Resubmission of round-5 kernel — bench failed on container infra, not kernel.
#include <hip/hip_runtime.h>
#include <hip/hip_bf16.h>
#include <stdint.h>

typedef __hip_bfloat16 bf16;

#define EPSBN 1e-5f
#define CHUNK 14080      // edges per k_bucket WG (56320 B LDS staging)
#define ROWSB 400        // rows per bucket (50 KB LDS acc; NB=500 -> ~2 blocks/CU)
#define BCAP  20480      // per-bucket padded capacity (worst case ~20.2K)
#define SENT  0xFFFFFFFFu
#define RSH   15         // src-range shift: 32768 rows = 2 MB of Y per range
#define NRMAX 7          // ceil(200000 / 32768)
#define NSEG  8          // NRMAX + 1

__device__ __forceinline__ float bits2f(unsigned int u) { return __uint_as_float(u); }

__device__ __forceinline__ void atomAddF(float* p, float v) {
#if defined(__HIP_DEVICE_COMPILE__)
    unsafeAtomicAdd(p, v);   // native global_atomic_add_f32 on gfx950
#else
    atomicAdd(p, v);
#endif
}

// native LDS float add (ds_add_f32), no CAS loop
__device__ __forceinline__ void ldsAdd(float* p, float v) {
    __hip_atomic_fetch_add(p, v, __ATOMIC_RELAXED, __HIP_MEMORY_SCOPE_WORKGROUP);
}

// ---- per-graph node counts ----
__global__ __launch_bounds__(256) void k_cntg(const int* __restrict__ batch,
                                              int* __restrict__ cntg, int n) {
    int i = blockIdx.x * 256 + threadIdx.x;
    if (i < n) atomicAdd(&cntg[batch[i]], 1);
}

// ======== CSR phase 1: LDS counting-sort per chunk, coalesced padded flush ====
__global__ __launch_bounds__(512) void k_bucket(const int* __restrict__ ei, int E,
                                                int* __restrict__ bcntP,
                                                int* __restrict__ bcntR,
                                                unsigned int* __restrict__ pairT,
                                                int NB) {
    __shared__ unsigned int stage[CHUNK];   // compact, grouped by bucket
    __shared__ int cR[512];                 // real count per bucket
    __shared__ int lbase[512];              // exclusive scan of cR
    __shared__ int gpos[512];               // global reserved base per bucket
    __shared__ int lhead[512];              // placement heads
    int t = threadIdx.x;
    int e0 = blockIdx.x * CHUNK;
    int e1 = e0 + CHUNK; if (e1 > E) e1 = E;
    const int* dst = ei + E;

    cR[t] = 0; lhead[t] = 0;
    __syncthreads();
    for (int e = e0 + t; e < e1; e += 512) atomicAdd(&cR[dst[e] / ROWSB], 1);
    __syncthreads();
    int c = cR[t];
    lbase[t] = c;
    __syncthreads();
    for (int off = 1; off < 512; off <<= 1) {
        int u = (t >= off) ? lbase[t - off] : 0;
        __syncthreads();
        lbase[t] += u;
        __syncthreads();
    }
    lbase[t] -= c;                           // exclusive
    if (t < NB && c > 0) {
        int p16 = (c + 15) & ~15;
        gpos[t] = atomicAdd(&bcntP[t], p16);
        atomicAdd(&bcntR[t], c);
    } else {
        gpos[t] = 0;
    }
    __syncthreads();
    for (int e = e0 + t; e < e1; e += 512) {
        int s = ei[e], d = dst[e];
        int b = d / ROWSB;
        int pos = atomicAdd(&lhead[b], 1);
        stage[lbase[b] + pos] = (unsigned int)s | ((unsigned int)(d - b * ROWSB) << 18);
    }
    __syncthreads();
    int wave = t >> 6, lane = t & 63;
    for (int b = wave; b < NB; b += 8) {
        int cc = cR[b];
        if (cc == 0) continue;
        int p16 = (cc + 15) & ~15;
        int lb = lbase[b];
        size_t gb = (size_t)b * BCAP + gpos[b];
        for (int j = lane; j < p16; j += 64) {
            unsigned int v = (j < cc) ? stage[lb + j] : SENT;
            if (gpos[b] + j < BCAP) pairT[gb + j] = v;
        }
    }
}

// ======== phase 2a: scan real bucket totals -> bucket bases ====
__global__ __launch_bounds__(1024) void k_bscan(const int* __restrict__ bcntR,
                                                int* __restrict__ bbase, int NB) {
    __shared__ int s[1024];
    int t = threadIdx.x;
    int c = (t < NB) ? bcntR[t] : 0;
    s[t] = c;
    __syncthreads();
    for (int off = 1; off < 1024; off <<= 1) {
        int u = (t >= off) ? s[t - off] : 0;
        __syncthreads();
        s[t] += u;
        __syncthreads();
    }
    if (t < NB) bbase[t] = s[t] - c;                // exclusive
}

// ======== phase 2b: per-bucket range-major packed-edge build ====
// Segment (bucket b, range r) holds PACKED entries (src | dstLocal<<18) in
// ARRIVAL order (random dst rows) -> no same-address LDS-atomic contention
// in the gather. segS[b*NSEG+r] = absolute start; segS[b*NSEG+NR] = end.
__global__ __launch_bounds__(512) void k_build(const unsigned int* __restrict__ pairT,
                                               const int* __restrict__ bcntP,
                                               const int* __restrict__ bbase,
                                               float* __restrict__ dinv,
                                               int* __restrict__ segS,
                                               unsigned int* __restrict__ colP,
                                               int n, int NR) {
    __shared__ int lcnt[ROWSB];        // per-row degree (for dinv)
    __shared__ int rhead[NSEG];        // per-range placement heads (absolute)
    __shared__ int rcnt[NSEG];
    int b = blockIdx.x, t = threadIdx.x;
    int bn0 = b * ROWSB;
    int nn = n - bn0; if (nn > ROWSB) nn = ROWSB; if (nn < 0) nn = 0;
    int m = min(bcntP[b], BCAP);
    const unsigned int* P = pairT + (size_t)b * BCAP;
    if (t < ROWSB) lcnt[t] = 0;
    if (t < NSEG) rcnt[t] = 0;
    __syncthreads();
    for (int i = t; i < m; i += 512) {
        unsigned int v = P[i];
        if (v != SENT) {
            atomicAdd(&lcnt[v >> 18], 1);
            atomicAdd(&rcnt[(v & 0x3FFFFu) >> RSH], 1);
        }
    }
    __syncthreads();
    if (t < nn) dinv[bn0 + t] = rsqrtf((float)(lcnt[t] + 1));   // + self-loop
    if (t == 0) {
        int run = bbase[b];
        for (int r = 0; r < NR; ++r) {
            segS[b * NSEG + r] = run;
            rhead[r] = run;
            run += rcnt[r];
        }
        segS[b * NSEG + NR] = run;
    }
    __syncthreads();
    for (int i = t; i < m; i += 512) {
        unsigned int v = P[i];
        if (v != SENT) {
            int pos = atomicAdd(&rhead[(v & 0x3FFFFu) >> RSH], 1);
            colP[pos] = v;
        }
    }
}

// ======== GEMMs (Y = bf16(dinv * (X @ W)), BN affine folded for 32-wide) ====

__global__ __launch_bounds__(256) void k_gemm1(const float* __restrict__ x,
                                               const float* __restrict__ W,
                                               const float* __restrict__ dinv,
                                               bf16* __restrict__ Y, int n) {
    __shared__ float Ws[128 * 32];
    __shared__ float xs[32 * 128];
    int tid = threadIdx.x;
    int base = blockIdx.x * 32;
    for (int i = tid; i < 128 * 32; i += 256) Ws[i] = W[i];
    if (base + 32 <= n) {
        const float4* x4 = (const float4*)(x + (size_t)base * 128);
        for (int i = tid; i < 1024; i += 256) {
            float4 v = x4[i];
            xs[i * 4 + 0] = v.x; xs[i * 4 + 1] = v.y;
            xs[i * 4 + 2] = v.z; xs[i * 4 + 3] = v.w;
        }
    } else {
        for (int i = tid; i < 32 * 128; i += 256) {
            int r = i >> 7, c = i & 127;
            int row = base + r;
            xs[i] = (row < n) ? x[(size_t)row * 128 + c] : 0.f;
        }
    }
    __syncthreads();
    int r0 = tid >> 5, j = tid & 31;
    float a0 = 0.f, a1 = 0.f, a2 = 0.f, a3 = 0.f;
#pragma unroll 8
    for (int k = 0; k < 128; ++k) {
        float w = Ws[k * 32 + j];
        a0 = fmaf(xs[(r0     ) * 128 + k], w, a0);
        a1 = fmaf(xs[(r0 +  8) * 128 + k], w, a1);
        a2 = fmaf(xs[(r0 + 16) * 128 + k], w, a2);
        a3 = fmaf(xs[(r0 + 24) * 128 + k], w, a3);
    }
    int row;
    row = base + r0;      if (row < n) Y[(size_t)row * 32 + j] = __float2bfloat16(a0 * dinv[row]);
    row = base + r0 + 8;  if (row < n) Y[(size_t)row * 32 + j] = __float2bfloat16(a1 * dinv[row]);
    row = base + r0 + 16; if (row < n) Y[(size_t)row * 32 + j] = __float2bfloat16(a2 * dinv[row]);
    row = base + r0 + 24; if (row < n) Y[(size_t)row * 32 + j] = __float2bfloat16(a3 * dinv[row]);
}

__global__ __launch_bounds__(256) void k_gemm32(const float* __restrict__ H,
                                                const float* __restrict__ W,
                                                const float* __restrict__ scale,
                                                const float* __restrict__ shift,
                                                const float* __restrict__ dinv,
                                                bf16* __restrict__ Y, int n) {
    __shared__ float Ws[32 * 32];
    __shared__ float xs[32 * 32];
    int tid = threadIdx.x;
    int base = blockIdx.x * 32;
    for (int i = tid; i < 1024; i += 256) Ws[i] = W[i];
    for (int i = tid; i < 1024; i += 256) {
        int r = i >> 5, k = i & 31;
        int row = base + r;
        xs[i] = (row < n) ? fmaf(H[(size_t)row * 32 + k], scale[k], shift[k]) : 0.f;
    }
    __syncthreads();
    int r0 = tid >> 5, j = tid & 31;
    float a0 = 0.f, a1 = 0.f, a2 = 0.f, a3 = 0.f;
#pragma unroll
    for (int k = 0; k < 32; ++k) {
        float w = Ws[k * 32 + j];
        a0 = fmaf(xs[(r0     ) * 32 + k], w, a0);
        a1 = fmaf(xs[(r0 +  8) * 32 + k], w, a1);
        a2 = fmaf(xs[(r0 + 16) * 32 + k], w, a2);
        a3 = fmaf(xs[(r0 + 24) * 32 + k], w, a3);
    }
    int row;
    row = base + r0;      if (row < n) Y[(size_t)row * 32 + j] = __float2bfloat16(a0 * dinv[row]);
    row = base + r0 + 8;  if (row < n) Y[(size_t)row * 32 + j] = __float2bfloat16(a1 * dinv[row]);
    row = base + r0 + 16; if (row < n) Y[(size_t)row * 32 + j] = __float2bfloat16(a2 * dinv[row]);
    row = base + r0 + 24; if (row < n) Y[(size_t)row * 32 + j] = __float2bfloat16(a3 * dinv[row]);
}

// ======== bucket-resident LDS-accumulate gather ========
// Block b owns rows [b*400, b*400+400): acc[400][32] f32 in LDS (50 KB),
// initialized with the self-loop Y rows. src-ranges swept in order; blocks
// co-resident and barrier-aligned -> per-XCD L2 holds the rotating 2 MB
// Y slice (FETCH 310->117 MB verified in r4). Edge-parallel, 4 lanes/edge,
// RANDOM dst-row order within a segment + XOR feature swizzle -> conflict-
// free native ds_add_f32. One-iteration colP+Y prefetch pipelines the chain.

__global__ __launch_bounds__(512) void k_gather_bn(const int* __restrict__ segS,
                                                   const unsigned int* __restrict__ colP,
                                                   const bf16* __restrict__ Y,
                                                   const float* __restrict__ bias,
                                                   const float* __restrict__ dinv,
                                                   float* __restrict__ H,
                                                   float* __restrict__ stats,
                                                   int n, int NR) {
    __shared__ float acc[ROWSB * 32];   // 50 KB; slot = row*32 + (feat ^ (row&31))
    int b = blockIdx.x, t = threadIdx.x;
    int bn0 = b * ROWSB;
    int nn = n - bn0; if (nn > ROWSB) nn = ROWSB;
    // self-loop init
    for (int i = t; i < ROWSB * 4; i += 512) {
        int row = i >> 2, q8 = (i & 3) * 8, k = row & 31, p = row * 32;
        uint4 v = make_uint4(0u, 0u, 0u, 0u);
        if (row < nn) v = *(const uint4*)(Y + ((size_t)(bn0 + row)) * 32 + q8);
        acc[p + ((q8 + 0) ^ k)] = bits2f(v.x << 16);
        acc[p + ((q8 + 1) ^ k)] = bits2f(v.x & 0xFFFF0000u);
        acc[p + ((q8 + 2) ^ k)] = bits2f(v.y << 16);
        acc[p + ((q8 + 3) ^ k)] = bits2f(v.y & 0xFFFF0000u);
        acc[p + ((q8 + 4) ^ k)] = bits2f(v.z << 16);
        acc[p + ((q8 + 5) ^ k)] = bits2f(v.z & 0xFFFF0000u);
        acc[p + ((q8 + 6) ^ k)] = bits2f(v.w << 16);
        acc[p + ((q8 + 7) ^ k)] = bits2f(v.w & 0xFFFF0000u);
    }
    __syncthreads();
    int q8 = (t & 3) * 8;
    int slot = t >> 2;                 // 0..127 edge slots per block
    const int* seg = segS + b * NSEG;
    for (int r = 0; r < NR; ++r) {
        int s1 = seg[r + 1];
        int i = seg[r] + slot;
        bool val = i < s1;
        unsigned int v = val ? colP[i] : 0u;
        uint4 y = make_uint4(0u, 0u, 0u, 0u);
        if (val) y = *(const uint4*)(Y + (size_t)(v & 0x3FFFFu) * 32 + q8);
        while (val) {
            int inext = i + 128;
            bool valn = inext < s1;
            unsigned int vn = valn ? colP[inext] : 0u;
            uint4 yn = make_uint4(0u, 0u, 0u, 0u);
            if (valn) yn = *(const uint4*)(Y + (size_t)(vn & 0x3FFFFu) * 32 + q8);
            int dl = (int)(v >> 18), k = dl & 31, p = dl * 32;
            ldsAdd(&acc[p + ((q8 + 0) ^ k)], bits2f(y.x << 16));
            ldsAdd(&acc[p + ((q8 + 1) ^ k)], bits2f(y.x & 0xFFFF0000u));
            ldsAdd(&acc[p + ((q8 + 2) ^ k)], bits2f(y.y << 16));
            ldsAdd(&acc[p + ((q8 + 3) ^ k)], bits2f(y.y & 0xFFFF0000u));
            ldsAdd(&acc[p + ((q8 + 4) ^ k)], bits2f(y.z << 16));
            ldsAdd(&acc[p + ((q8 + 5) ^ k)], bits2f(y.z & 0xFFFF0000u));
            ldsAdd(&acc[p + ((q8 + 6) ^ k)], bits2f(y.w << 16));
            ldsAdd(&acc[p + ((q8 + 7) ^ k)], bits2f(y.w & 0xFFFF0000u));
            i = inext; v = vn; y = yn; val = valn;
        }
        __syncthreads();   // keep block's waves range-aligned
    }
    // epilogue: feat-parallel, conflict-free
    int fr = t >> 5, f = t & 31;
    float bs = bias[f];
    float sA = 0.f, sQ = 0.f;
    for (int rr = fr; rr < nn; rr += 16) {
        int row = bn0 + rr;
        float a = acc[rr * 32 + (f ^ (rr & 31))];
        float h = tanhf(fmaf(dinv[row], a, bs));
        H[(size_t)row * 32 + f] = h;
        sA += h; sQ += h * h;
    }
    __syncthreads();                   // acc reads done; reuse head as stats
    if (t < 64) acc[t] = 0.f;
    __syncthreads();
    ldsAdd(&acc[f], sA);
    ldsAdd(&acc[32 + f], sQ);
    __syncthreads();
    if (t < 64) atomAddF(&stats[t], acc[t]);
}

__global__ __launch_bounds__(512) void k_gather_pool(const int* __restrict__ segS,
                                                     const unsigned int* __restrict__ colP,
                                                     const bf16* __restrict__ Y,
                                                     const float* __restrict__ bias,
                                                     const float* __restrict__ dinv,
                                                     const int* __restrict__ batch,
                                                     float* __restrict__ pool,
                                                     int n, int NR) {
    __shared__ float acc[ROWSB * 32];   // 50 KB
    int b = blockIdx.x, t = threadIdx.x;
    int bn0 = b * ROWSB;
    int nn = n - bn0; if (nn > ROWSB) nn = ROWSB;
    for (int i = t; i < ROWSB * 4; i += 512) {
        int row = i >> 2, q8 = (i & 3) * 8, k = row & 31, p = row * 32;
        uint4 v = make_uint4(0u, 0u, 0u, 0u);
        if (row < nn) v = *(const uint4*)(Y + ((size_t)(bn0 + row)) * 32 + q8);
        acc[p + ((q8 + 0) ^ k)] = bits2f(v.x << 16);
        acc[p + ((q8 + 1) ^ k)] = bits2f(v.x & 0xFFFF0000u);
        acc[p + ((q8 + 2) ^ k)] = bits2f(v.y << 16);
        acc[p + ((q8 + 3) ^ k)] = bits2f(v.y & 0xFFFF0000u);
        acc[p + ((q8 + 4) ^ k)] = bits2f(v.z << 16);
        acc[p + ((q8 + 5) ^ k)] = bits2f(v.z & 0xFFFF0000u);
        acc[p + ((q8 + 6) ^ k)] = bits2f(v.w << 16);
        acc[p + ((q8 + 7) ^ k)] = bits2f(v.w & 0xFFFF0000u);
    }
    __syncthreads();
    int q8 = (t & 3) * 8;
    int slot = t >> 2;
    const int* seg = segS + b * NSEG;
    for (int r = 0; r < NR; ++r) {
        int s1 = seg[r + 1];
        int i = seg[r] + slot;
        bool val = i < s1;
        unsigned int v = val ? colP[i] : 0u;
        uint4 y = make_uint4(0u, 0u, 0u, 0u);
        if (val) y = *(const uint4*)(Y + (size_t)(v & 0x3FFFFu) * 32 + q8);
        while (val) {
            int inext = i + 128;
            bool valn = inext < s1;
            unsigned int vn = valn ? colP[inext] : 0u;
            uint4 yn = make_uint4(0u, 0u, 0u, 0u);
            if (valn) yn = *(const uint4*)(Y + (size_t)(vn & 0x3FFFFu) * 32 + q8);
            int dl = (int)(v >> 18), k = dl & 31, p = dl * 32;
            ldsAdd(&acc[p + ((q8 + 0) ^ k)], bits2f(y.x << 16));
            ldsAdd(&acc[p + ((q8 + 1) ^ k)], bits2f(y.x & 0xFFFF0000u));
            ldsAdd(&acc[p + ((q8 + 2) ^ k)], bits2f(y.y << 16));
            ldsAdd(&acc[p + ((q8 + 3) ^ k)], bits2f(y.y & 0xFFFF0000u));
            ldsAdd(&acc[p + ((q8 + 4) ^ k)], bits2f(y.z << 16));
            ldsAdd(&acc[p + ((q8 + 5) ^ k)], bits2f(y.z & 0xFFFF0000u));
            ldsAdd(&acc[p + ((q8 + 6) ^ k)], bits2f(y.w << 16));
            ldsAdd(&acc[p + ((q8 + 7) ^ k)], bits2f(y.w & 0xFFFF0000u));
            i = inext; v = vn; y = yn; val = valn;
        }
        __syncthreads();
    }
    int fr = t >> 5, f = t & 31;
    float bs = bias[f];
    for (int rr = fr; rr < nn; rr += 16) {
        int row = bn0 + rr;
        float a = acc[rr * 32 + (f ^ (rr & 31))];
        float h = tanhf(fmaf(dinv[row], a, bs));
        atomAddF(&pool[(size_t)batch[row] * 32 + f], h);
    }
}

// ---- finalize BN -> per-feature affine (scale, shift) ----
__global__ void k_bnfin(const float* __restrict__ stats, const float* __restrict__ g,
                        const float* __restrict__ be, float* __restrict__ scale,
                        float* __restrict__ shift, float invN) {
    int f = threadIdx.x;  // 32 threads
    float mu = stats[f] * invN;
    float var = stats[32 + f] * invN - mu * mu;
    float inv = rsqrtf(var + EPSBN);
    float sc = g[f] * inv;
    scale[f] = sc;
    shift[f] = be[f] - mu * sc;
}

// ---- head: out[g] = (pool[g]/cnt[g]) @ Wc + bc ----
__global__ __launch_bounds__(256) void k_final(const float* __restrict__ pool,
                                               const int* __restrict__ cntg,
                                               const float* __restrict__ Wc,
                                               const float* __restrict__ bc,
                                               float* __restrict__ out, int G) {
    int g = blockIdx.x * 256 + threadIdx.x;
    if (g >= G) return;
    float inv = 1.f / (float)max(cntg[g], 1);
    float acc = bc[0];
#pragma unroll
    for (int f = 0; f < 32; ++f) acc = fmaf(pool[(size_t)g * 32 + f] * inv, Wc[f], acc);
    out[g] = acc;
}

extern "C" void kernel_launch(void* const* d_in, const int* in_sizes, int n_in,
                              void* d_out, int out_size, void* d_ws, size_t ws_size,
                              hipStream_t stream) {
    const float* x    = (const float*)d_in[0];
    const int*   ei   = (const int*)d_in[1];
    const int*   batch= (const int*)d_in[2];
    const float* W1   = (const float*)d_in[3];
    const float* b1   = (const float*)d_in[4];
    const float* g1   = (const float*)d_in[5];
    const float* be1  = (const float*)d_in[6];
    const float* W2   = (const float*)d_in[7];
    const float* b2   = (const float*)d_in[8];
    const float* g2   = (const float*)d_in[9];
    const float* be2  = (const float*)d_in[10];
    const float* W3   = (const float*)d_in[11];
    const float* b3   = (const float*)d_in[12];
    // d_in[13], d_in[14] = g3, be3 (unused by reference)
    const float* Wc   = (const float*)d_in[15];
    const float* bc   = (const float*)d_in[16];
    float* out = (float*)d_out;

    const int n = in_sizes[0] / 128;   // 200000
    const int E = in_sizes[1] / 2;     // 6400000
    const int G = out_size;            // 2048
    const int NB = (n + ROWSB - 1) / ROWSB;       // 500 buckets of 400 nodes
    const int NR = (n + (1 << RSH) - 1) >> RSH;   // 7 src ranges

    char* p = (char*)d_ws;
    auto alloc = [&p](size_t bytes) -> char* {
        uintptr_t q = ((uintptr_t)p + 255) & ~(uintptr_t)255;
        p = (char*)(q + bytes);
        return (char*)q;
    };
    // zero-initialized region first (contiguous from d_ws start)
    int*   cntg  = (int*)alloc((size_t)G * 4);
    float* stats = (float*)alloc(128 * 4);            // BN1: [0,64), BN2: [64,128)
    float* pool  = (float*)alloc((size_t)G * 32 * 4);
    int*   bcntP = (int*)alloc((size_t)NB * 4);       // padded reservations
    int*   bcntR = (int*)alloc((size_t)NB * 4);       // real counts
    size_t zero_bytes = (size_t)(p - (char*)d_ws);
    float* dinv   = (float*)alloc((size_t)n * 4);
    float* scale1 = (float*)alloc(32 * 4);
    float* shift1 = (float*)alloc(32 * 4);
    float* scale2 = (float*)alloc(32 * 4);
    float* shift2 = (float*)alloc(32 * 4);
    int*   bbase  = (int*)alloc((size_t)(NB + 1) * 4);
    int*   segS   = (int*)alloc((size_t)NB * NSEG * 4);          // 16 KB
    unsigned int* pairT = (unsigned int*)alloc((size_t)NB * BCAP * 4);  // ~41 MB
    unsigned int* colP  = (unsigned int*)alloc((size_t)E * 4);   // packed edges
    bf16*  bufY   = (bf16*)alloc((size_t)n * 32 * 2);
    float* bufH   = (float*)alloc((size_t)n * 32 * 4);

    hipMemsetAsync(d_ws, 0, zero_bytes, stream);

    int gN    = (n + 255) / 256;
    int gR32  = (n + 31) / 32;
    int gBuk  = (E + CHUNK - 1) / CHUNK;
    float invN = 1.0f / (float)n;

    // ---- build bucketed edge lists (once; shared by all 3 layers) ----
    k_cntg  <<<gN, 256, 0, stream>>>(batch, cntg, n);
    k_bucket<<<gBuk, 512, 0, stream>>>(ei, E, bcntP, bcntR, pairT, NB);
    k_bscan <<<1, 1024, 0, stream>>>(bcntR, bbase, NB);
    k_build <<<NB, 512, 0, stream>>>(pairT, bcntP, bbase, dinv, segS, colP, n, NR);

    // ---- layer 1 ----
    k_gemm1<<<gR32, 256, 0, stream>>>(x, W1, dinv, bufY, n);
    k_gather_bn<<<NB, 512, 0, stream>>>(segS, colP, bufY, b1, dinv, bufH, stats, n, NR);
    k_bnfin<<<1, 32, 0, stream>>>(stats, g1, be1, scale1, shift1, invN);

    // ---- layer 2 ----
    k_gemm32<<<gR32, 256, 0, stream>>>(bufH, W2, scale1, shift1, dinv, bufY, n);
    k_gather_bn<<<NB, 512, 0, stream>>>(segS, colP, bufY, b2, dinv, bufH, stats + 64, n, NR);
    k_bnfin<<<1, 32, 0, stream>>>(stats + 64, g2, be2, scale2, shift2, invN);

    // ---- layer 3 (tanh fused into pooling; no BN) ----
    k_gemm32<<<gR32, 256, 0, stream>>>(bufH, W3, scale2, shift2, dinv, bufY, n);
    k_gather_pool<<<NB, 512, 0, stream>>>(segS, colP, bufY, b3, dinv, batch, pool, n, NR);

    // ---- head ----
    k_final<<<(G + 255) / 256, 256, 0, stream>>>(pool, cntg, Wc, bc, out, G);
}

// Round 7
// 894.916 us; speedup vs baseline: 5.1069x; 4.0980x over previous
//
#include <hip/hip_runtime.h>
#include <hip/hip_bf16.h>
#include <stdint.h>

typedef __hip_bfloat16 bf16;

#define EPSBN 1e-5f
#define CHUNK 14080      // edges per k_bucket WG (56320 B LDS staging)
#define BSH   9          // 512-node buckets
#define BCAP  22528      // per-bucket padded capacity (proven r2-r4)
#define SENT  0xFFFFFFFFu
#define RSH   15         // src-range shift: 32768 rows = 2 MB of Y per range
#define NRMAX 7          // ceil(200000 / 32768)
#define STAGECAP 2816    // per-range colP staging words (mean ~2341 + >5 sigma)

__device__ __forceinline__ float bits2f(unsigned int u) { return __uint_as_float(u); }
__device__ __forceinline__ float lo16(unsigned int u) { return bits2f(u << 16); }
__device__ __forceinline__ float hi16(unsigned int u) { return bits2f(u & 0xFFFF0000u); }

__device__ __forceinline__ void atomAddF(float* p, float v) {
#if defined(__HIP_DEVICE_COMPILE__)
    unsafeAtomicAdd(p, v);   // native global_atomic_add_f32 on gfx950
#else
    atomicAdd(p, v);
#endif
}

// small-volume LDS float add (epilogue stats only)
__device__ __forceinline__ void ldsAdd(float* p, float v) {
    __hip_atomic_fetch_add(p, v, __ATOMIC_RELAXED, __HIP_MEMORY_SCOPE_WORKGROUP);
}

// ---- per-graph node counts ----
__global__ __launch_bounds__(256) void k_cntg(const int* __restrict__ batch,
                                              int* __restrict__ cntg, int n) {
    int i = blockIdx.x * 256 + threadIdx.x;
    if (i < n) atomicAdd(&cntg[batch[i]], 1);
}

// ======== CSR phase 1: LDS counting-sort per chunk, coalesced padded flush ====
__global__ __launch_bounds__(512) void k_bucket(const int* __restrict__ ei, int E,
                                                int* __restrict__ bcntP,
                                                int* __restrict__ bcntR,
                                                unsigned int* __restrict__ pairT,
                                                int NB) {
    __shared__ unsigned int stage[CHUNK];
    __shared__ int cR[512];
    __shared__ int lbase[512];
    __shared__ int gpos[512];
    __shared__ int lhead[512];
    int t = threadIdx.x;
    int e0 = blockIdx.x * CHUNK;
    int e1 = e0 + CHUNK; if (e1 > E) e1 = E;
    const int* dst = ei + E;

    cR[t] = 0; lhead[t] = 0;
    __syncthreads();
    for (int e = e0 + t; e < e1; e += 512) atomicAdd(&cR[dst[e] >> BSH], 1);
    __syncthreads();
    int c = cR[t];
    lbase[t] = c;
    __syncthreads();
    for (int off = 1; off < 512; off <<= 1) {
        int u = (t >= off) ? lbase[t - off] : 0;
        __syncthreads();
        lbase[t] += u;
        __syncthreads();
    }
    lbase[t] -= c;
    if (t < NB && c > 0) {
        int p16 = (c + 15) & ~15;
        gpos[t] = atomicAdd(&bcntP[t], p16);
        atomicAdd(&bcntR[t], c);
    } else {
        gpos[t] = 0;
    }
    __syncthreads();
    for (int e = e0 + t; e < e1; e += 512) {
        int s = ei[e], d = dst[e];
        int b = d >> BSH;
        int pos = atomicAdd(&lhead[b], 1);
        stage[lbase[b] + pos] = (unsigned int)s | ((unsigned int)(d & 511) << 18);
    }
    __syncthreads();
    int wave = t >> 6, lane = t & 63;
    for (int b = wave; b < NB; b += 8) {
        int cc = cR[b];
        if (cc == 0) continue;
        int p16 = (cc + 15) & ~15;
        int lb = lbase[b];
        size_t gb = (size_t)b * BCAP + gpos[b];
        for (int j = lane; j < p16; j += 64) {
            unsigned int v = (j < cc) ? stage[lb + j] : SENT;
            if (gpos[b] + j < BCAP) pairT[gb + j] = v;
        }
    }
}

// ======== phase 2a: scan real bucket totals -> bucket bases ====
__global__ __launch_bounds__(1024) void k_bscan(const int* __restrict__ bcntR,
                                                int* __restrict__ bbase, int NB) {
    __shared__ int s[1024];
    int t = threadIdx.x;
    int c = (t < NB) ? bcntR[t] : 0;
    s[t] = c;
    __syncthreads();
    for (int off = 1; off < 1024; off <<= 1) {
        int u = (t >= off) ? s[t - off] : 0;
        __syncthreads();
        s[t] += u;
        __syncthreads();
    }
    if (t < NB) bbase[t] = s[t] - c;
}

// ======== phase 2b: per-bucket (range, row)-sorted packed CSR + segW ====
// colP for bucket b: range-major, row-ascending within range; entries PACKED
// (src | dstLocal<<18). segW[b*57 + r*8 + w] = absolute start of sub-segment
// (range r, wavegrp w = dstLocal>>6); segW[b*57+56] = bucket end.
__global__ __launch_bounds__(512) void k_build(const unsigned int* __restrict__ pairT,
                                               const int* __restrict__ bcntP,
                                               const int* __restrict__ bbase,
                                               float* __restrict__ dinv,
                                               int* __restrict__ segW,
                                               unsigned int* __restrict__ colP,
                                               int n, int NR) {
    __shared__ int lcnt2[512 * NRMAX];
    __shared__ int head2[512 * NRMAX];
    __shared__ int stmp[512];
    int b = blockIdx.x, t = threadIdx.x;
    int bn0 = b << BSH;
    int nn = n - bn0; if (nn > 512) nn = 512; if (nn < 0) nn = 0;
    int m = min(bcntP[b], BCAP);
    const unsigned int* P = pairT + (size_t)b * BCAP;
    for (int i = t; i < 512 * NRMAX; i += 512) lcnt2[i] = 0;
    __syncthreads();
    for (int i = t; i < m; i += 512) {
        unsigned int v = P[i];
        if (v != SENT)
            atomicAdd(&lcnt2[(v >> 18) * NRMAX + ((v & 0x3FFFFu) >> RSH)], 1);
    }
    __syncthreads();
    int rowc = 0;
#pragma unroll
    for (int r = 0; r < NRMAX; ++r) rowc += lcnt2[t * NRMAX + r];
    if (t < nn) dinv[bn0 + t] = rsqrtf((float)(rowc + 1));   // + self-loop
    int runbase = bbase[b];
    for (int r = 0; r < NR; ++r) {
        int c = lcnt2[t * NRMAX + r];
        stmp[t] = c;
        __syncthreads();
        for (int off = 1; off < 512; off <<= 1) {
            int u = (t >= off) ? stmp[t - off] : 0;
            __syncthreads();
            stmp[t] += u;
            __syncthreads();
        }
        int start = runbase + stmp[t] - c;
        head2[t * NRMAX + r] = start;
        if ((t & 63) == 0) segW[b * 57 + r * 8 + (t >> 6)] = start;
        int tot = stmp[511];
        __syncthreads();
        runbase += tot;
    }
    if (t == 0) segW[b * 57 + 56] = runbase;
    __syncthreads();
    for (int i = t; i < m; i += 512) {
        unsigned int v = P[i];
        if (v != SENT) {
            int pos = atomicAdd(&head2[(v >> 18) * NRMAX + ((v & 0x3FFFFu) >> RSH)], 1);
            colP[pos] = v;
        }
    }
}

// ======== GEMMs (Y = bf16(dinv * (X @ W)), BN affine folded for 32-wide) ====

__global__ __launch_bounds__(256) void k_gemm1(const float* __restrict__ x,
                                               const float* __restrict__ W,
                                               const float* __restrict__ dinv,
                                               bf16* __restrict__ Y, int n) {
    __shared__ float Ws[128 * 32];
    __shared__ float xs[32 * 128];
    int tid = threadIdx.x;
    int base = blockIdx.x * 32;
    for (int i = tid; i < 128 * 32; i += 256) Ws[i] = W[i];
    if (base + 32 <= n) {
        const float4* x4 = (const float4*)(x + (size_t)base * 128);
        for (int i = tid; i < 1024; i += 256) {
            float4 v = x4[i];
            xs[i * 4 + 0] = v.x; xs[i * 4 + 1] = v.y;
            xs[i * 4 + 2] = v.z; xs[i * 4 + 3] = v.w;
        }
    } else {
        for (int i = tid; i < 32 * 128; i += 256) {
            int r = i >> 7, c = i & 127;
            int row = base + r;
            xs[i] = (row < n) ? x[(size_t)row * 128 + c] : 0.f;
        }
    }
    __syncthreads();
    int r0 = tid >> 5, j = tid & 31;
    float a0 = 0.f, a1 = 0.f, a2 = 0.f, a3 = 0.f;
#pragma unroll 8
    for (int k = 0; k < 128; ++k) {
        float w = Ws[k * 32 + j];
        a0 = fmaf(xs[(r0     ) * 128 + k], w, a0);
        a1 = fmaf(xs[(r0 +  8) * 128 + k], w, a1);
        a2 = fmaf(xs[(r0 + 16) * 128 + k], w, a2);
        a3 = fmaf(xs[(r0 + 24) * 128 + k], w, a3);
    }
    int row;
    row = base + r0;      if (row < n) Y[(size_t)row * 32 + j] = __float2bfloat16(a0 * dinv[row]);
    row = base + r0 + 8;  if (row < n) Y[(size_t)row * 32 + j] = __float2bfloat16(a1 * dinv[row]);
    row = base + r0 + 16; if (row < n) Y[(size_t)row * 32 + j] = __float2bfloat16(a2 * dinv[row]);
    row = base + r0 + 24; if (row < n) Y[(size_t)row * 32 + j] = __float2bfloat16(a3 * dinv[row]);
}

__global__ __launch_bounds__(256) void k_gemm32(const float* __restrict__ H,
                                                const float* __restrict__ W,
                                                const float* __restrict__ scale,
                                                const float* __restrict__ shift,
                                                const float* __restrict__ dinv,
                                                bf16* __restrict__ Y, int n) {
    __shared__ float Ws[32 * 32];
    __shared__ float xs[32 * 32];
    int tid = threadIdx.x;
    int base = blockIdx.x * 32;
    for (int i = tid; i < 1024; i += 256) Ws[i] = W[i];
    for (int i = tid; i < 1024; i += 256) {
        int r = i >> 5, k = i & 31;
        int row = base + r;
        xs[i] = (row < n) ? fmaf(H[(size_t)row * 32 + k], scale[k], shift[k]) : 0.f;
    }
    __syncthreads();
    int r0 = tid >> 5, j = tid & 31;
    float a0 = 0.f, a1 = 0.f, a2 = 0.f, a3 = 0.f;
#pragma unroll
    for (int k = 0; k < 32; ++k) {
        float w = Ws[k * 32 + j];
        a0 = fmaf(xs[(r0     ) * 32 + k], w, a0);
        a1 = fmaf(xs[(r0 +  8) * 32 + k], w, a1);
        a2 = fmaf(xs[(r0 + 16) * 32 + k], w, a2);
        a3 = fmaf(xs[(r0 + 24) * 32 + k], w, a3);
    }
    int row;
    row = base + r0;      if (row < n) Y[(size_t)row * 32 + j] = __float2bfloat16(a0 * dinv[row]);
    row = base + r0 + 8;  if (row < n) Y[(size_t)row * 32 + j] = __float2bfloat16(a1 * dinv[row]);
    row = base + r0 + 16; if (row < n) Y[(size_t)row * 32 + j] = __float2bfloat16(a2 * dinv[row]);
    row = base + r0 + 24; if (row < n) Y[(size_t)row * 32 + j] = __float2bfloat16(a3 * dinv[row]);
}

// ======== atomic-free bucket-resident gather core ========
// Block b owns 512 rows; acc[512][32] f32, feature slot rotated by 4*(row&7)
// (keeps 16B alignment for b128 RMW, spreads banks). Wave w owns rows
// [64w,64w+64): zero cross-wave sharing. Windows stride-transposed (S =
// ceil(cnt/16)): duplicates within a window only adjacent-k (run<=2S bound);
// resolved via quad_perm DPP prev/next word exchange (suppress/absorb).
// Ranges swept with per-range barrier -> L2-resident Y slice (FETCH 120 MB).
__device__ __forceinline__ void gather_acc(float* acc, unsigned int* stageL,
                                           const int* sw,
                                           const unsigned int* __restrict__ colP,
                                           const bf16* __restrict__ Y,
                                           int t, int NR) {
    int wv = t >> 6, lane = t & 63;
    int kq = lane >> 2, q = lane & 3, q8 = q * 8;
    for (int r = 0; r < NR; ++r) {
        int rs = sw[r * 8], re = sw[r * 8 + 8];
        int cRtot = re - rs;
        int lim = cRtot < STAGECAP ? cRtot : STAGECAP;
        for (int i = t; i < lim; i += 512) stageL[i] = colP[rs + i];
        __syncthreads();
        int s0 = sw[r * 8 + wv] - rs;
        int cnt = sw[r * 8 + wv + 1] - rs - s0;
        int S = (cnt + 15) >> 4;
        for (int w2 = 0; w2 < S; ++w2) {
            int li = w2 + (kq - 1 + q) * S;
            unsigned int wvd = SENT;
            if (li >= 0 && li < cnt) {
                int gi = s0 + li;
                wvd = (gi < STAGECAP) ? stageL[gi] : colP[rs + gi];
            }
            unsigned int myW   = (unsigned int)__builtin_amdgcn_mov_dpp((int)wvd, 0x55, 0xF, 0xF, false);
            unsigned int prevW = (unsigned int)__builtin_amdgcn_mov_dpp((int)wvd, 0x00, 0xF, 0xF, false);
            unsigned int nextW = (unsigned int)__builtin_amdgcn_mov_dpp((int)wvd, 0xAA, 0xF, 0xF, false);
            bool val = (w2 + kq * S) < cnt;
            int row = (int)(myW >> 18);
            int src = (int)(myW & 0x3FFFFu);
            bool sup = (prevW >> 18) == (myW >> 18);
            bool ab  = val && ((nextW >> 18) == (myW >> 18));
            float a0 = 0.f, a1 = 0.f, a2 = 0.f, a3 = 0.f;
            float a4 = 0.f, a5 = 0.f, a6 = 0.f, a7 = 0.f;
            if (val) {
                uint4 y = *(const uint4*)(Y + (size_t)src * 32 + q8);
                a0 = lo16(y.x); a1 = hi16(y.x); a2 = lo16(y.y); a3 = hi16(y.y);
                a4 = lo16(y.z); a5 = hi16(y.z); a6 = lo16(y.w); a7 = hi16(y.w);
            }
            if (__any(ab)) {                     // rare: absorb k+1 duplicate
                if (ab) {
                    int ns = (int)(nextW & 0x3FFFFu);
                    uint4 y2 = *(const uint4*)(Y + (size_t)ns * 32 + q8);
                    a0 += lo16(y2.x); a1 += hi16(y2.x); a2 += lo16(y2.y); a3 += hi16(y2.y);
                    a4 += lo16(y2.z); a5 += hi16(y2.z); a6 += lo16(y2.w); a7 += hi16(y2.w);
                }
            }
            if (val && !sup) {
                int rot = 4 * (row & 7);
                float* A = acc + row * 32;
                int f0 = (q8 + rot) & 31, f1 = (q8 + 4 + rot) & 31;
                float4* P0 = (float4*)(A + f0);
                float4* P1 = (float4*)(A + f1);
                float4 u0 = *P0, u1 = *P1;
                u0.x += a0; u0.y += a1; u0.z += a2; u0.w += a3;
                u1.x += a4; u1.y += a5; u1.z += a6; u1.w += a7;
                *P0 = u0; *P1 = u1;
            }
        }
        __syncthreads();   // acc settled + stage reusable; range alignment
    }
}

__device__ __forceinline__ void acc_init(float* acc, const bf16* __restrict__ Y,
                                         int bn0, int nn, int t) {
    for (int i = t; i < 2048; i += 512) {
        int row = i >> 2, qq = (i & 3) * 8;
        uint4 v = make_uint4(0u, 0u, 0u, 0u);
        if (row < nn) v = *(const uint4*)(Y + (size_t)(bn0 + row) * 32 + qq);
        int rot = 4 * (row & 7);
        float* A = acc + row * 32;
        int f0 = (qq + rot) & 31, f1 = (qq + 4 + rot) & 31;
        A[f0 + 0] = lo16(v.x); A[f0 + 1] = hi16(v.x);
        A[f0 + 2] = lo16(v.y); A[f0 + 3] = hi16(v.y);
        A[f1 + 0] = lo16(v.z); A[f1 + 1] = hi16(v.z);
        A[f1 + 2] = lo16(v.w); A[f1 + 3] = hi16(v.w);
    }
}

// ======== gather + tanh + BN-stats (layers 1,2) ========
__global__ __launch_bounds__(512) void k_gather_bn(const int* __restrict__ segW,
                                                   const unsigned int* __restrict__ colP,
                                                   const bf16* __restrict__ Y,
                                                   const float* __restrict__ bias,
                                                   const float* __restrict__ dinv,
                                                   float* __restrict__ H,
                                                   float* __restrict__ stats,
                                                   int n, int NR) {
    __shared__ float acc[512 * 32];          // 64 KB
    __shared__ unsigned int stageL[STAGECAP];
    __shared__ int sw[64];
    int b = blockIdx.x, t = threadIdx.x;
    int bn0 = b << BSH;
    int nn = n - bn0; if (nn > 512) nn = 512;
    if (t < 57) sw[t] = segW[b * 57 + t];
    acc_init(acc, Y, bn0, nn, t);
    __syncthreads();
    gather_acc(acc, stageL, sw, colP, Y, t, NR);
    // epilogue: feat-parallel
    int fr = t >> 5, f = t & 31;
    float bs = bias[f];
    float sA = 0.f, sQ = 0.f;
    for (int rr = fr; rr < nn; rr += 16) {
        float a = acc[rr * 32 + ((f + 4 * (rr & 7)) & 31)];
        float h = tanhf(fmaf(dinv[bn0 + rr], a, bs));
        H[(size_t)(bn0 + rr) * 32 + f] = h;
        sA += h; sQ += h * h;
    }
    __syncthreads();
    if (t < 64) acc[t] = 0.f;
    __syncthreads();
    ldsAdd(&acc[f], sA);
    ldsAdd(&acc[32 + f], sQ);
    __syncthreads();
    if (t < 64) atomAddF(&stats[t], acc[t]);
}

// ======== gather + tanh + mean-pool accumulate (layer 3) ========
__global__ __launch_bounds__(512) void k_gather_pool(const int* __restrict__ segW,
                                                     const unsigned int* __restrict__ colP,
                                                     const bf16* __restrict__ Y,
                                                     const float* __restrict__ bias,
                                                     const float* __restrict__ dinv,
                                                     const int* __restrict__ batch,
                                                     float* __restrict__ pool,
                                                     int n, int NR) {
    __shared__ float acc[512 * 32];
    __shared__ unsigned int stageL[STAGECAP];
    __shared__ int sw[64];
    int b = blockIdx.x, t = threadIdx.x;
    int bn0 = b << BSH;
    int nn = n - bn0; if (nn > 512) nn = 512;
    if (t < 57) sw[t] = segW[b * 57 + t];
    acc_init(acc, Y, bn0, nn, t);
    __syncthreads();
    gather_acc(acc, stageL, sw, colP, Y, t, NR);
    int fr = t >> 5, f = t & 31;
    float bs = bias[f];
    for (int rr = fr; rr < nn; rr += 16) {
        int row = bn0 + rr;
        float a = acc[rr * 32 + ((f + 4 * (rr & 7)) & 31)];
        float h = tanhf(fmaf(dinv[row], a, bs));
        atomAddF(&pool[(size_t)batch[row] * 32 + f], h);
    }
}

// ---- finalize BN -> per-feature affine (scale, shift) ----
__global__ void k_bnfin(const float* __restrict__ stats, const float* __restrict__ g,
                        const float* __restrict__ be, float* __restrict__ scale,
                        float* __restrict__ shift, float invN) {
    int f = threadIdx.x;  // 32 threads
    float mu = stats[f] * invN;
    float var = stats[32 + f] * invN - mu * mu;
    float inv = rsqrtf(var + EPSBN);
    float sc = g[f] * inv;
    scale[f] = sc;
    shift[f] = be[f] - mu * sc;
}

// ---- head: out[g] = (pool[g]/cnt[g]) @ Wc + bc ----
__global__ __launch_bounds__(256) void k_final(const float* __restrict__ pool,
                                               const int* __restrict__ cntg,
                                               const float* __restrict__ Wc,
                                               const float* __restrict__ bc,
                                               float* __restrict__ out, int G) {
    int g = blockIdx.x * 256 + threadIdx.x;
    if (g >= G) return;
    float inv = 1.f / (float)max(cntg[g], 1);
    float acc = bc[0];
#pragma unroll
    for (int f = 0; f < 32; ++f) acc = fmaf(pool[(size_t)g * 32 + f] * inv, Wc[f], acc);
    out[g] = acc;
}

extern "C" void kernel_launch(void* const* d_in, const int* in_sizes, int n_in,
                              void* d_out, int out_size, void* d_ws, size_t ws_size,
                              hipStream_t stream) {
    const float* x    = (const float*)d_in[0];
    const int*   ei   = (const int*)d_in[1];
    const int*   batch= (const int*)d_in[2];
    const float* W1   = (const float*)d_in[3];
    const float* b1   = (const float*)d_in[4];
    const float* g1   = (const float*)d_in[5];
    const float* be1  = (const float*)d_in[6];
    const float* W2   = (const float*)d_in[7];
    const float* b2   = (const float*)d_in[8];
    const float* g2   = (const float*)d_in[9];
    const float* be2  = (const float*)d_in[10];
    const float* W3   = (const float*)d_in[11];
    const float* b3   = (const float*)d_in[12];
    // d_in[13], d_in[14] = g3, be3 (unused by reference)
    const float* Wc   = (const float*)d_in[15];
    const float* bc   = (const float*)d_in[16];
    float* out = (float*)d_out;

    const int n = in_sizes[0] / 128;   // 200000
    const int E = in_sizes[1] / 2;     // 6400000
    const int G = out_size;            // 2048
    const int NB = (n + 511) >> 9;     // 391 buckets of 512 nodes
    const int NR = (n + (1 << RSH) - 1) >> RSH;   // 7 src ranges

    char* p = (char*)d_ws;
    auto alloc = [&p](size_t bytes) -> char* {
        uintptr_t q = ((uintptr_t)p + 255) & ~(uintptr_t)255;
        p = (char*)(q + bytes);
        return (char*)q;
    };
    // zero-initialized region first (contiguous from d_ws start)
    int*   cntg  = (int*)alloc((size_t)G * 4);
    float* stats = (float*)alloc(128 * 4);            // BN1: [0,64), BN2: [64,128)
    float* pool  = (float*)alloc((size_t)G * 32 * 4);
    int*   bcntP = (int*)alloc((size_t)NB * 4);       // padded reservations
    int*   bcntR = (int*)alloc((size_t)NB * 4);       // real counts
    size_t zero_bytes = (size_t)(p - (char*)d_ws);
    float* dinv   = (float*)alloc((size_t)n * 4);
    float* scale1 = (float*)alloc(32 * 4);
    float* shift1 = (float*)alloc(32 * 4);
    float* scale2 = (float*)alloc(32 * 4);
    float* shift2 = (float*)alloc(32 * 4);
    int*   bbase  = (int*)alloc((size_t)(NB + 1) * 4);
    int*   segW   = (int*)alloc((size_t)NB * 57 * 4);            // ~89 KB
    unsigned int* pairT = (unsigned int*)alloc((size_t)NB * BCAP * 4);  // ~35 MB
    unsigned int* colP  = (unsigned int*)alloc((size_t)E * 4);   // packed edges
    bf16*  bufY   = (bf16*)alloc((size_t)n * 32 * 2);
    float* bufH   = (float*)alloc((size_t)n * 32 * 4);

    hipMemsetAsync(d_ws, 0, zero_bytes, stream);

    int gN    = (n + 255) / 256;
    int gR32  = (n + 31) / 32;
    int gBuk  = (E + CHUNK - 1) / CHUNK;
    float invN = 1.0f / (float)n;

    // ---- build (range,row)-sorted bucketed edges (once; shared by 3 layers) ----
    k_cntg  <<<gN, 256, 0, stream>>>(batch, cntg, n);
    k_bucket<<<gBuk, 512, 0, stream>>>(ei, E, bcntP, bcntR, pairT, NB);
    k_bscan <<<1, 1024, 0, stream>>>(bcntR, bbase, NB);
    k_build <<<NB, 512, 0, stream>>>(pairT, bcntP, bbase, dinv, segW, colP, n, NR);

    // ---- layer 1 ----
    k_gemm1<<<gR32, 256, 0, stream>>>(x, W1, dinv, bufY, n);
    k_gather_bn<<<NB, 512, 0, stream>>>(segW, colP, bufY, b1, dinv, bufH, stats, n, NR);
    k_bnfin<<<1, 32, 0, stream>>>(stats, g1, be1, scale1, shift1, invN);

    // ---- layer 2 ----
    k_gemm32<<<gR32, 256, 0, stream>>>(bufH, W2, scale1, shift1, dinv, bufY, n);
    k_gather_bn<<<NB, 512, 0, stream>>>(segW, colP, bufY, b2, dinv, bufH, stats + 64, n, NR);
    k_bnfin<<<1, 32, 0, stream>>>(stats + 64, g2, be2, scale2, shift2, invN);

    // ---- layer 3 (tanh fused into pooling; no BN) ----
    k_gemm32<<<gR32, 256, 0, stream>>>(bufH, W3, scale2, shift2, dinv, bufY, n);
    k_gather_pool<<<NB, 512, 0, stream>>>(segW, colP, bufY, b3, dinv, batch, pool, n, NR);

    // ---- head ----
    k_final<<<(G + 255) / 256, 256, 0, stream>>>(pool, cntg, Wc, bc, out, G);
}

// Round 8
// 853.708 us; speedup vs baseline: 5.3534x; 1.0483x over previous
//
#include <hip/hip_runtime.h>
#include <hip/hip_bf16.h>
#include <stdint.h>

typedef __hip_bfloat16 bf16;

#define EPSBN 1e-5f
#define CHUNK 14080      // edges per k_bucket WG (56320 B LDS staging)
#define ROWSB 392        // rows per bucket -> NB=511 ~= 2 blocks/CU balanced
#define ACCPAD 13750     // acc floats (55000 B) padded so exactly 2 blocks/CU
#define BCAP  20992      // per-bucket padded capacity (mean 12.5K+5sig+pad 6.8K)
#define SENT  0xFFFFFFFFu
#define RSH   15         // src-range shift: 32768 rows = 2 MB of Y per range
#define NRMAX 7          // ceil(200000 / 32768)

__device__ __forceinline__ float bits2f(unsigned int u) { return __uint_as_float(u); }
__device__ __forceinline__ float lo16(unsigned int u) { return bits2f(u << 16); }
__device__ __forceinline__ float hi16(unsigned int u) { return bits2f(u & 0xFFFF0000u); }

__device__ __forceinline__ void atomAddF(float* p, float v) {
#if defined(__HIP_DEVICE_COMPILE__)
    unsafeAtomicAdd(p, v);   // native global_atomic_add_f32 on gfx950
#else
    atomicAdd(p, v);
#endif
}

// small-volume LDS float add (epilogue stats only)
__device__ __forceinline__ void ldsAdd(float* p, float v) {
    __hip_atomic_fetch_add(p, v, __ATOMIC_RELAXED, __HIP_MEMORY_SCOPE_WORKGROUP);
}

// ---- per-graph node counts ----
__global__ __launch_bounds__(256) void k_cntg(const int* __restrict__ batch,
                                              int* __restrict__ cntg, int n) {
    int i = blockIdx.x * 256 + threadIdx.x;
    if (i < n) atomicAdd(&cntg[batch[i]], 1);
}

// ======== CSR phase 1: LDS counting-sort per chunk, coalesced padded flush ====
__global__ __launch_bounds__(512) void k_bucket(const int* __restrict__ ei, int E,
                                                int* __restrict__ bcntP,
                                                int* __restrict__ bcntR,
                                                unsigned int* __restrict__ pairT,
                                                int NB) {
    __shared__ unsigned int stage[CHUNK];
    __shared__ int cR[512];
    __shared__ int lbase[512];
    __shared__ int gpos[512];
    __shared__ int lhead[512];
    int t = threadIdx.x;
    int e0 = blockIdx.x * CHUNK;
    int e1 = e0 + CHUNK; if (e1 > E) e1 = E;
    const int* dst = ei + E;

    cR[t] = 0; lhead[t] = 0;
    __syncthreads();
    for (int e = e0 + t; e < e1; e += 512) atomicAdd(&cR[dst[e] / ROWSB], 1);
    __syncthreads();
    int c = cR[t];
    lbase[t] = c;
    __syncthreads();
    for (int off = 1; off < 512; off <<= 1) {
        int u = (t >= off) ? lbase[t - off] : 0;
        __syncthreads();
        lbase[t] += u;
        __syncthreads();
    }
    lbase[t] -= c;
    if (t < NB && c > 0) {
        int p16 = (c + 15) & ~15;
        gpos[t] = atomicAdd(&bcntP[t], p16);
        atomicAdd(&bcntR[t], c);
    } else {
        gpos[t] = 0;
    }
    __syncthreads();
    for (int e = e0 + t; e < e1; e += 512) {
        int s = ei[e], d = dst[e];
        int b = d / ROWSB;
        int pos = atomicAdd(&lhead[b], 1);
        stage[lbase[b] + pos] = (unsigned int)s | ((unsigned int)(d - b * ROWSB) << 18);
    }
    __syncthreads();
    int wave = t >> 6, lane = t & 63;
    for (int b = wave; b < NB; b += 8) {
        int cc = cR[b];
        if (cc == 0) continue;
        int p16 = (cc + 15) & ~15;
        int lb = lbase[b];
        size_t gb = (size_t)b * BCAP + gpos[b];
        for (int j = lane; j < p16; j += 64) {
            unsigned int v = (j < cc) ? stage[lb + j] : SENT;
            if (gpos[b] + j < BCAP) pairT[gb + j] = v;
        }
    }
}

// ======== phase 2a: scan real bucket totals -> bucket bases ====
__global__ __launch_bounds__(1024) void k_bscan(const int* __restrict__ bcntR,
                                                int* __restrict__ bbase, int NB) {
    __shared__ int s[1024];
    int t = threadIdx.x;
    int c = (t < NB) ? bcntR[t] : 0;
    s[t] = c;
    __syncthreads();
    for (int off = 1; off < 1024; off <<= 1) {
        int u = (t >= off) ? s[t - off] : 0;
        __syncthreads();
        s[t] += u;
        __syncthreads();
    }
    if (t < NB) bbase[t] = s[t] - c;
}

// ======== phase 2b: per-bucket (range, row)-sorted packed CSR + segW ====
// colP for bucket b: range-major, row-ascending within range; entries PACKED
// (src | dstLocal<<18). segW[b*57 + r*8 + w] = absolute start of sub-segment
// (range r, wavegrp w = dstLocal/49); segW[b*57+56] = bucket end.
__global__ __launch_bounds__(512) void k_build(const unsigned int* __restrict__ pairT,
                                               const int* __restrict__ bcntP,
                                               const int* __restrict__ bbase,
                                               float* __restrict__ dinv,
                                               int* __restrict__ segW,
                                               unsigned int* __restrict__ colP,
                                               int n, int NR) {
    __shared__ int lcnt2[ROWSB * NRMAX];
    __shared__ int head2[ROWSB * NRMAX];
    __shared__ int stmp[512];
    int b = blockIdx.x, t = threadIdx.x;
    int bn0 = b * ROWSB;
    int nn = n - bn0; if (nn > ROWSB) nn = ROWSB; if (nn < 0) nn = 0;
    int m = min(bcntP[b], BCAP);
    const unsigned int* P = pairT + (size_t)b * BCAP;
    for (int i = t; i < ROWSB * NRMAX; i += 512) lcnt2[i] = 0;
    __syncthreads();
    for (int i = t; i < m; i += 512) {
        unsigned int v = P[i];
        if (v != SENT)
            atomicAdd(&lcnt2[(v >> 18) * NRMAX + ((v & 0x3FFFFu) >> RSH)], 1);
    }
    __syncthreads();
    if (t < nn) {
        int rowc = 0;
#pragma unroll
        for (int r = 0; r < NRMAX; ++r) rowc += lcnt2[t * NRMAX + r];
        dinv[bn0 + t] = rsqrtf((float)(rowc + 1));   // + self-loop
    }
    int runbase = bbase[b];
    for (int r = 0; r < NR; ++r) {
        int c = (t < ROWSB) ? lcnt2[t * NRMAX + r] : 0;
        stmp[t] = c;
        __syncthreads();
        for (int off = 1; off < 512; off <<= 1) {
            int u = (t >= off) ? stmp[t - off] : 0;
            __syncthreads();
            stmp[t] += u;
            __syncthreads();
        }
        int start = runbase + stmp[t] - c;
        if (t < ROWSB) {
            head2[t * NRMAX + r] = start;
            if (t % 49 == 0) segW[b * 57 + r * 8 + t / 49] = start;
        }
        int tot = stmp[511];
        __syncthreads();
        runbase += tot;
    }
    if (t == 0) segW[b * 57 + 56] = runbase;
    __syncthreads();
    for (int i = t; i < m; i += 512) {
        unsigned int v = P[i];
        if (v != SENT) {
            int pos = atomicAdd(&head2[(v >> 18) * NRMAX + ((v & 0x3FFFFu) >> RSH)], 1);
            colP[pos] = v;
        }
    }
}

// ======== GEMMs (Y = bf16(dinv * (X @ W)), BN affine folded for 32-wide) ====

__global__ __launch_bounds__(256) void k_gemm1(const float* __restrict__ x,
                                               const float* __restrict__ W,
                                               const float* __restrict__ dinv,
                                               bf16* __restrict__ Y, int n) {
    __shared__ float Ws[128 * 32];
    __shared__ float xs[32 * 128];
    int tid = threadIdx.x;
    int base = blockIdx.x * 32;
    for (int i = tid; i < 128 * 32; i += 256) Ws[i] = W[i];
    if (base + 32 <= n) {
        const float4* x4 = (const float4*)(x + (size_t)base * 128);
        for (int i = tid; i < 1024; i += 256) {
            float4 v = x4[i];
            xs[i * 4 + 0] = v.x; xs[i * 4 + 1] = v.y;
            xs[i * 4 + 2] = v.z; xs[i * 4 + 3] = v.w;
        }
    } else {
        for (int i = tid; i < 32 * 128; i += 256) {
            int r = i >> 7, c = i & 127;
            int row = base + r;
            xs[i] = (row < n) ? x[(size_t)row * 128 + c] : 0.f;
        }
    }
    __syncthreads();
    int r0 = tid >> 5, j = tid & 31;
    float a0 = 0.f, a1 = 0.f, a2 = 0.f, a3 = 0.f;
#pragma unroll 8
    for (int k = 0; k < 128; ++k) {
        float w = Ws[k * 32 + j];
        a0 = fmaf(xs[(r0     ) * 128 + k], w, a0);
        a1 = fmaf(xs[(r0 +  8) * 128 + k], w, a1);
        a2 = fmaf(xs[(r0 + 16) * 128 + k], w, a2);
        a3 = fmaf(xs[(r0 + 24) * 128 + k], w, a3);
    }
    int row;
    row = base + r0;      if (row < n) Y[(size_t)row * 32 + j] = __float2bfloat16(a0 * dinv[row]);
    row = base + r0 + 8;  if (row < n) Y[(size_t)row * 32 + j] = __float2bfloat16(a1 * dinv[row]);
    row = base + r0 + 16; if (row < n) Y[(size_t)row * 32 + j] = __float2bfloat16(a2 * dinv[row]);
    row = base + r0 + 24; if (row < n) Y[(size_t)row * 32 + j] = __float2bfloat16(a3 * dinv[row]);
}

__global__ __launch_bounds__(256) void k_gemm32(const float* __restrict__ H,
                                                const float* __restrict__ W,
                                                const float* __restrict__ scale,
                                                const float* __restrict__ shift,
                                                const float* __restrict__ dinv,
                                                bf16* __restrict__ Y, int n) {
    __shared__ float Ws[32 * 32];
    __shared__ float xs[32 * 32];
    int tid = threadIdx.x;
    int base = blockIdx.x * 32;
    for (int i = tid; i < 1024; i += 256) Ws[i] = W[i];
    for (int i = tid; i < 1024; i += 256) {
        int r = i >> 5, k = i & 31;
        int row = base + r;
        xs[i] = (row < n) ? fmaf(H[(size_t)row * 32 + k], scale[k], shift[k]) : 0.f;
    }
    __syncthreads();
    int r0 = tid >> 5, j = tid & 31;
    float a0 = 0.f, a1 = 0.f, a2 = 0.f, a3 = 0.f;
#pragma unroll
    for (int k = 0; k < 32; ++k) {
        float w = Ws[k * 32 + j];
        a0 = fmaf(xs[(r0     ) * 32 + k], w, a0);
        a1 = fmaf(xs[(r0 +  8) * 32 + k], w, a1);
        a2 = fmaf(xs[(r0 + 16) * 32 + k], w, a2);
        a3 = fmaf(xs[(r0 + 24) * 32 + k], w, a3);
    }
    int row;
    row = base + r0;      if (row < n) Y[(size_t)row * 32 + j] = __float2bfloat16(a0 * dinv[row]);
    row = base + r0 + 8;  if (row < n) Y[(size_t)row * 32 + j] = __float2bfloat16(a1 * dinv[row]);
    row = base + r0 + 16; if (row < n) Y[(size_t)row * 32 + j] = __float2bfloat16(a2 * dinv[row]);
    row = base + r0 + 24; if (row < n) Y[(size_t)row * 32 + j] = __float2bfloat16(a3 * dinv[row]);
}

// ======== atomic-free bucket-resident gather core ========
// Block b owns 392 rows; acc[392][32] f32 (padded to 55 KB -> exactly 2
// blocks/CU), feature slot rotated by 4*(row&7). Wave w owns rows
// [49w,49w+49): zero cross-wave sharing. Windows stride-transposed (S =
// ceil(cnt/16)): in-window duplicates only between adjacent quads (run>S),
// resolved via quad_perm DPP suppress/absorb (run<=2S bound holds).
// colP read DIRECT from global (streamed, ~once per word). One barrier per
// range keeps block waves phase-aligned for the L2-resident Y slice.
__device__ __forceinline__ void gather_acc(float* acc, const int* sw,
                                           const unsigned int* __restrict__ colP,
                                           const bf16* __restrict__ Y,
                                           int t, int NR) {
    int wv = t >> 6, lane = t & 63;
    int kq = lane >> 2, q = lane & 3, q8 = q * 8;
    for (int r = 0; r < NR; ++r) {
        int s0 = sw[r * 8 + wv];
        int cnt = sw[r * 8 + wv + 1] - s0;
        const unsigned int* cp = colP + s0;
        int S = (cnt + 15) >> 4;
        for (int w2 = 0; w2 < S; ++w2) {
            int li = w2 + (kq - 1 + q) * S;
            unsigned int wvd = SENT;
            if (li >= 0 && li < cnt) wvd = cp[li];
            unsigned int myW   = (unsigned int)__builtin_amdgcn_mov_dpp((int)wvd, 0x55, 0xF, 0xF, false);
            unsigned int prevW = (unsigned int)__builtin_amdgcn_mov_dpp((int)wvd, 0x00, 0xF, 0xF, false);
            unsigned int nextW = (unsigned int)__builtin_amdgcn_mov_dpp((int)wvd, 0xAA, 0xF, 0xF, false);
            bool val = (w2 + kq * S) < cnt;
            int row = (int)(myW >> 18);
            int src = (int)(myW & 0x3FFFFu);
            bool sup = (prevW >> 18) == (myW >> 18);
            bool ab  = val && ((nextW >> 18) == (myW >> 18));
            float a0 = 0.f, a1 = 0.f, a2 = 0.f, a3 = 0.f;
            float a4 = 0.f, a5 = 0.f, a6 = 0.f, a7 = 0.f;
            if (val) {
                uint4 y = *(const uint4*)(Y + (size_t)src * 32 + q8);
                a0 = lo16(y.x); a1 = hi16(y.x); a2 = lo16(y.y); a3 = hi16(y.y);
                a4 = lo16(y.z); a5 = hi16(y.z); a6 = lo16(y.w); a7 = hi16(y.w);
            }
            if (__any(ab)) {                     // rare: absorb adjacent-quad dup
                if (ab) {
                    int ns = (int)(nextW & 0x3FFFFu);
                    uint4 y2 = *(const uint4*)(Y + (size_t)ns * 32 + q8);
                    a0 += lo16(y2.x); a1 += hi16(y2.x); a2 += lo16(y2.y); a3 += hi16(y2.y);
                    a4 += lo16(y2.z); a5 += hi16(y2.z); a6 += lo16(y2.w); a7 += hi16(y2.w);
                }
            }
            if (val && !sup) {
                int rot = 4 * (row & 7);
                float* A = acc + row * 32;
                int f0 = (q8 + rot) & 31, f1 = (q8 + 4 + rot) & 31;
                float4* P0 = (float4*)(A + f0);
                float4* P1 = (float4*)(A + f1);
                float4 u0 = *P0, u1 = *P1;
                u0.x += a0; u0.y += a1; u0.z += a2; u0.w += a3;
                u1.x += a4; u1.y += a5; u1.z += a6; u1.w += a7;
                *P0 = u0; *P1 = u1;
            }
        }
        __syncthreads();   // range alignment within the block
    }
}

__device__ __forceinline__ void acc_init(float* acc, const bf16* __restrict__ Y,
                                         int bn0, int nn, int t) {
    for (int i = t; i < ROWSB * 4; i += 512) {
        int row = i >> 2, qq = (i & 3) * 8;
        uint4 v = make_uint4(0u, 0u, 0u, 0u);
        if (row < nn) v = *(const uint4*)(Y + (size_t)(bn0 + row) * 32 + qq);
        int rot = 4 * (row & 7);
        float* A = acc + row * 32;
        int f0 = (qq + rot) & 31, f1 = (qq + 4 + rot) & 31;
        A[f0 + 0] = lo16(v.x); A[f0 + 1] = hi16(v.x);
        A[f0 + 2] = lo16(v.y); A[f0 + 3] = hi16(v.y);
        A[f1 + 0] = lo16(v.z); A[f1 + 1] = hi16(v.z);
        A[f1 + 2] = lo16(v.w); A[f1 + 3] = hi16(v.w);
    }
}

// ======== gather + tanh + BN-stats (layers 1,2) ========
__global__ __launch_bounds__(512) void k_gather_bn(const int* __restrict__ segW,
                                                   const unsigned int* __restrict__ colP,
                                                   const bf16* __restrict__ Y,
                                                   const float* __restrict__ bias,
                                                   const float* __restrict__ dinv,
                                                   float* __restrict__ H,
                                                   float* __restrict__ stats,
                                                   int n, int NR) {
    __shared__ float acc[ACCPAD];            // 55 KB (padded: 2 blocks/CU exactly)
    __shared__ int sw[64];
    int b = blockIdx.x, t = threadIdx.x;
    int bn0 = b * ROWSB;
    int nn = n - bn0; if (nn > ROWSB) nn = ROWSB;
    if (t < 57) sw[t] = segW[b * 57 + t];
    acc_init(acc, Y, bn0, nn, t);
    __syncthreads();
    gather_acc(acc, sw, colP, Y, t, NR);
    // epilogue: feat-parallel
    int fr = t >> 5, f = t & 31;
    float bs = bias[f];
    float sA = 0.f, sQ = 0.f;
    for (int rr = fr; rr < nn; rr += 16) {
        float a = acc[rr * 32 + ((f + 4 * (rr & 7)) & 31)];
        float h = tanhf(fmaf(dinv[bn0 + rr], a, bs));
        H[(size_t)(bn0 + rr) * 32 + f] = h;
        sA += h; sQ += h * h;
    }
    __syncthreads();
    if (t < 64) acc[t] = 0.f;
    __syncthreads();
    ldsAdd(&acc[f], sA);
    ldsAdd(&acc[32 + f], sQ);
    __syncthreads();
    if (t < 64) atomAddF(&stats[t], acc[t]);
}

// ======== gather + tanh + mean-pool accumulate (layer 3) ========
__global__ __launch_bounds__(512) void k_gather_pool(const int* __restrict__ segW,
                                                     const unsigned int* __restrict__ colP,
                                                     const bf16* __restrict__ Y,
                                                     const float* __restrict__ bias,
                                                     const float* __restrict__ dinv,
                                                     const int* __restrict__ batch,
                                                     float* __restrict__ pool,
                                                     int n, int NR) {
    __shared__ float acc[ACCPAD];
    __shared__ int sw[64];
    int b = blockIdx.x, t = threadIdx.x;
    int bn0 = b * ROWSB;
    int nn = n - bn0; if (nn > ROWSB) nn = ROWSB;
    if (t < 57) sw[t] = segW[b * 57 + t];
    acc_init(acc, Y, bn0, nn, t);
    __syncthreads();
    gather_acc(acc, sw, colP, Y, t, NR);
    int fr = t >> 5, f = t & 31;
    float bs = bias[f];
    for (int rr = fr; rr < nn; rr += 16) {
        int row = bn0 + rr;
        float a = acc[rr * 32 + ((f + 4 * (rr & 7)) & 31)];
        float h = tanhf(fmaf(dinv[row], a, bs));
        atomAddF(&pool[(size_t)batch[row] * 32 + f], h);
    }
}

// ---- finalize BN -> per-feature affine (scale, shift) ----
__global__ void k_bnfin(const float* __restrict__ stats, const float* __restrict__ g,
                        const float* __restrict__ be, float* __restrict__ scale,
                        float* __restrict__ shift, float invN) {
    int f = threadIdx.x;  // 32 threads
    float mu = stats[f] * invN;
    float var = stats[32 + f] * invN - mu * mu;
    float inv = rsqrtf(var + EPSBN);
    float sc = g[f] * inv;
    scale[f] = sc;
    shift[f] = be[f] - mu * sc;
}

// ---- head: out[g] = (pool[g]/cnt[g]) @ Wc + bc ----
__global__ __launch_bounds__(256) void k_final(const float* __restrict__ pool,
                                               const int* __restrict__ cntg,
                                               const float* __restrict__ Wc,
                                               const float* __restrict__ bc,
                                               float* __restrict__ out, int G) {
    int g = blockIdx.x * 256 + threadIdx.x;
    if (g >= G) return;
    float inv = 1.f / (float)max(cntg[g], 1);
    float acc = bc[0];
#pragma unroll
    for (int f = 0; f < 32; ++f) acc = fmaf(pool[(size_t)g * 32 + f] * inv, Wc[f], acc);
    out[g] = acc;
}

extern "C" void kernel_launch(void* const* d_in, const int* in_sizes, int n_in,
                              void* d_out, int out_size, void* d_ws, size_t ws_size,
                              hipStream_t stream) {
    const float* x    = (const float*)d_in[0];
    const int*   ei   = (const int*)d_in[1];
    const int*   batch= (const int*)d_in[2];
    const float* W1   = (const float*)d_in[3];
    const float* b1   = (const float*)d_in[4];
    const float* g1   = (const float*)d_in[5];
    const float* be1  = (const float*)d_in[6];
    const float* W2   = (const float*)d_in[7];
    const float* b2   = (const float*)d_in[8];
    const float* g2   = (const float*)d_in[9];
    const float* be2  = (const float*)d_in[10];
    const float* W3   = (const float*)d_in[11];
    const float* b3   = (const float*)d_in[12];
    // d_in[13], d_in[14] = g3, be3 (unused by reference)
    const float* Wc   = (const float*)d_in[15];
    const float* bc   = (const float*)d_in[16];
    float* out = (float*)d_out;

    const int n = in_sizes[0] / 128;   // 200000
    const int E = in_sizes[1] / 2;     // 6400000
    const int G = out_size;            // 2048
    const int NB = (n + ROWSB - 1) / ROWSB;       // 511 buckets of 392 nodes
    const int NR = (n + (1 << RSH) - 1) >> RSH;   // 7 src ranges

    char* p = (char*)d_ws;
    auto alloc = [&p](size_t bytes) -> char* {
        uintptr_t q = ((uintptr_t)p + 255) & ~(uintptr_t)255;
        p = (char*)(q + bytes);
        return (char*)q;
    };
    // zero-initialized region first (contiguous from d_ws start)
    int*   cntg  = (int*)alloc((size_t)G * 4);
    float* stats = (float*)alloc(128 * 4);            // BN1: [0,64), BN2: [64,128)
    float* pool  = (float*)alloc((size_t)G * 32 * 4);
    int*   bcntP = (int*)alloc((size_t)NB * 4);       // padded reservations
    int*   bcntR = (int*)alloc((size_t)NB * 4);       // real counts
    size_t zero_bytes = (size_t)(p - (char*)d_ws);
    float* dinv   = (float*)alloc((size_t)n * 4);
    float* scale1 = (float*)alloc(32 * 4);
    float* shift1 = (float*)alloc(32 * 4);
    float* scale2 = (float*)alloc(32 * 4);
    float* shift2 = (float*)alloc(32 * 4);
    int*   bbase  = (int*)alloc((size_t)(NB + 1) * 4);
    int*   segW   = (int*)alloc((size_t)NB * 57 * 4);            // ~117 KB
    unsigned int* pairT = (unsigned int*)alloc((size_t)NB * BCAP * 4);  // ~43 MB
    unsigned int* colP  = (unsigned int*)alloc((size_t)E * 4);   // packed edges
    bf16*  bufY   = (bf16*)alloc((size_t)n * 32 * 2);
    float* bufH   = (float*)alloc((size_t)n * 32 * 4);

    hipMemsetAsync(d_ws, 0, zero_bytes, stream);

    int gN    = (n + 255) / 256;
    int gR32  = (n + 31) / 32;
    int gBuk  = (E + CHUNK - 1) / CHUNK;
    float invN = 1.0f / (float)n;

    // ---- build (range,row)-sorted bucketed edges (once; shared by 3 layers) ----
    k_cntg  <<<gN, 256, 0, stream>>>(batch, cntg, n);
    k_bucket<<<gBuk, 512, 0, stream>>>(ei, E, bcntP, bcntR, pairT, NB);
    k_bscan <<<1, 1024, 0, stream>>>(bcntR, bbase, NB);
    k_build <<<NB, 512, 0, stream>>>(pairT, bcntP, bbase, dinv, segW, colP, n, NR);

    // ---- layer 1 ----
    k_gemm1<<<gR32, 256, 0, stream>>>(x, W1, dinv, bufY, n);
    k_gather_bn<<<NB, 512, 0, stream>>>(segW, colP, bufY, b1, dinv, bufH, stats, n, NR);
    k_bnfin<<<1, 32, 0, stream>>>(stats, g1, be1, scale1, shift1, invN);

    // ---- layer 2 ----
    k_gemm32<<<gR32, 256, 0, stream>>>(bufH, W2, scale1, shift1, dinv, bufY, n);
    k_gather_bn<<<NB, 512, 0, stream>>>(segW, colP, bufY, b2, dinv, bufH, stats + 64, n, NR);
    k_bnfin<<<1, 32, 0, stream>>>(stats + 64, g2, be2, scale2, shift2, invN);

    // ---- layer 3 (tanh fused into pooling; no BN) ----
    k_gemm32<<<gR32, 256, 0, stream>>>(bufH, W3, scale2, shift2, dinv, bufY, n);
    k_gather_pool<<<NB, 512, 0, stream>>>(segW, colP, bufY, b3, dinv, batch, pool, n, NR);

    // ---- head ----
    k_final<<<(G + 255) / 256, 256, 0, stream>>>(pool, cntg, Wc, bc, out, G);
}

// Round 9
// 821.619 us; speedup vs baseline: 5.5625x; 1.0391x over previous
//
#include <hip/hip_runtime.h>
#include <hip/hip_bf16.h>
#include <stdint.h>

typedef __hip_bfloat16 bf16;

#define EPSBN 1e-5f
#define CHUNK 14080      // edges per k_bucket WG (56320 B LDS staging)
#define ROWSB 392        // rows per bucket -> NB=511 ~= 2 blocks/CU balanced
#define ACCPAD 13750     // acc floats (55000 B) padded so exactly 2 blocks/CU
#define BCAP  20992      // per-bucket padded capacity (mean 12.5K+5sig+pad 6.8K)
#define SENT  0xFFFFFFFFu
#define RSH   15         // src-range shift: 32768 rows = 2 MB of Y per range
#define NRMAX 7          // ceil(200000 / 32768)

__device__ __forceinline__ float bits2f(unsigned int u) { return __uint_as_float(u); }
__device__ __forceinline__ float lo16(unsigned int u) { return bits2f(u << 16); }
__device__ __forceinline__ float hi16(unsigned int u) { return bits2f(u & 0xFFFF0000u); }

__device__ __forceinline__ void atomAddF(float* p, float v) {
#if defined(__HIP_DEVICE_COMPILE__)
    unsafeAtomicAdd(p, v);   // native global_atomic_add_f32 on gfx950
#else
    atomicAdd(p, v);
#endif
}

// small-volume LDS float add (epilogue stats only)
__device__ __forceinline__ void ldsAdd(float* p, float v) {
    __hip_atomic_fetch_add(p, v, __ATOMIC_RELAXED, __HIP_MEMORY_SCOPE_WORKGROUP);
}

// ---- per-graph node counts ----
__global__ __launch_bounds__(256) void k_cntg(const int* __restrict__ batch,
                                              int* __restrict__ cntg, int n) {
    int i = blockIdx.x * 256 + threadIdx.x;
    if (i < n) atomicAdd(&cntg[batch[i]], 1);
}

// ======== CSR phase 1: LDS counting-sort per chunk, coalesced padded flush ====
__global__ __launch_bounds__(512) void k_bucket(const int* __restrict__ ei, int E,
                                                int* __restrict__ bcntP,
                                                int* __restrict__ bcntR,
                                                unsigned int* __restrict__ pairT,
                                                int NB) {
    __shared__ unsigned int stage[CHUNK];
    __shared__ int cR[512];
    __shared__ int lbase[512];
    __shared__ int gpos[512];
    __shared__ int lhead[512];
    int t = threadIdx.x;
    int e0 = blockIdx.x * CHUNK;
    int e1 = e0 + CHUNK; if (e1 > E) e1 = E;
    const int* dst = ei + E;

    cR[t] = 0; lhead[t] = 0;
    __syncthreads();
    for (int e = e0 + t; e < e1; e += 512) atomicAdd(&cR[dst[e] / ROWSB], 1);
    __syncthreads();
    int c = cR[t];
    lbase[t] = c;
    __syncthreads();
    for (int off = 1; off < 512; off <<= 1) {
        int u = (t >= off) ? lbase[t - off] : 0;
        __syncthreads();
        lbase[t] += u;
        __syncthreads();
    }
    lbase[t] -= c;
    if (t < NB && c > 0) {
        int p16 = (c + 15) & ~15;
        gpos[t] = atomicAdd(&bcntP[t], p16);
        atomicAdd(&bcntR[t], c);
    } else {
        gpos[t] = 0;
    }
    __syncthreads();
    for (int e = e0 + t; e < e1; e += 512) {
        int s = ei[e], d = dst[e];
        int b = d / ROWSB;
        int pos = atomicAdd(&lhead[b], 1);
        stage[lbase[b] + pos] = (unsigned int)s | ((unsigned int)(d - b * ROWSB) << 18);
    }
    __syncthreads();
    int wave = t >> 6, lane = t & 63;
    for (int b = wave; b < NB; b += 8) {
        int cc = cR[b];
        if (cc == 0) continue;
        int p16 = (cc + 15) & ~15;
        int lb = lbase[b];
        size_t gb = (size_t)b * BCAP + gpos[b];
        for (int j = lane; j < p16; j += 64) {
            unsigned int v = (j < cc) ? stage[lb + j] : SENT;
            if (gpos[b] + j < BCAP) pairT[gb + j] = v;
        }
    }
}

// ======== phase 2a: scan real bucket totals -> bucket bases ====
__global__ __launch_bounds__(1024) void k_bscan(const int* __restrict__ bcntR,
                                                int* __restrict__ bbase, int NB) {
    __shared__ int s[1024];
    int t = threadIdx.x;
    int c = (t < NB) ? bcntR[t] : 0;
    s[t] = c;
    __syncthreads();
    for (int off = 1; off < 1024; off <<= 1) {
        int u = (t >= off) ? s[t - off] : 0;
        __syncthreads();
        s[t] += u;
        __syncthreads();
    }
    if (t < NB) bbase[t] = s[t] - c;
}

// ======== phase 2b: per-bucket (range, row)-sorted packed CSR + segW ====
// colP for bucket b: range-major, row-ascending within range; entries PACKED
// (src | dstLocal<<18). segW[b*57 + r*8 + w] = absolute start of sub-segment
// (range r, wavegrp w = dstLocal/49); segW[b*57+56] = bucket end.
__global__ __launch_bounds__(512) void k_build(const unsigned int* __restrict__ pairT,
                                               const int* __restrict__ bcntP,
                                               const int* __restrict__ bbase,
                                               float* __restrict__ dinv,
                                               int* __restrict__ segW,
                                               unsigned int* __restrict__ colP,
                                               int n, int NR) {
    __shared__ int lcnt2[ROWSB * NRMAX];
    __shared__ int head2[ROWSB * NRMAX];
    __shared__ int stmp[512];
    int b = blockIdx.x, t = threadIdx.x;
    int bn0 = b * ROWSB;
    int nn = n - bn0; if (nn > ROWSB) nn = ROWSB; if (nn < 0) nn = 0;
    int m = min(bcntP[b], BCAP);
    const unsigned int* P = pairT + (size_t)b * BCAP;
    for (int i = t; i < ROWSB * NRMAX; i += 512) lcnt2[i] = 0;
    __syncthreads();
    for (int i = t; i < m; i += 512) {
        unsigned int v = P[i];
        if (v != SENT)
            atomicAdd(&lcnt2[(v >> 18) * NRMAX + ((v & 0x3FFFFu) >> RSH)], 1);
    }
    __syncthreads();
    if (t < nn) {
        int rowc = 0;
#pragma unroll
        for (int r = 0; r < NRMAX; ++r) rowc += lcnt2[t * NRMAX + r];
        dinv[bn0 + t] = rsqrtf((float)(rowc + 1));   // + self-loop
    }
    int runbase = bbase[b];
    for (int r = 0; r < NR; ++r) {
        int c = (t < ROWSB) ? lcnt2[t * NRMAX + r] : 0;
        stmp[t] = c;
        __syncthreads();
        for (int off = 1; off < 512; off <<= 1) {
            int u = (t >= off) ? stmp[t - off] : 0;
            __syncthreads();
            stmp[t] += u;
            __syncthreads();
        }
        int start = runbase + stmp[t] - c;
        if (t < ROWSB) {
            head2[t * NRMAX + r] = start;
            if (t % 49 == 0) segW[b * 57 + r * 8 + t / 49] = start;
        }
        int tot = stmp[511];
        __syncthreads();
        runbase += tot;
    }
    if (t == 0) segW[b * 57 + 56] = runbase;
    __syncthreads();
    for (int i = t; i < m; i += 512) {
        unsigned int v = P[i];
        if (v != SENT) {
            int pos = atomicAdd(&head2[(v >> 18) * NRMAX + ((v & 0x3FFFFu) >> RSH)], 1);
            colP[pos] = v;
        }
    }
}

// ======== GEMMs (Y = bf16(dinv * (X @ W)), BN affine folded for 32-wide) ====

__global__ __launch_bounds__(256) void k_gemm1(const float* __restrict__ x,
                                               const float* __restrict__ W,
                                               const float* __restrict__ dinv,
                                               bf16* __restrict__ Y, int n) {
    __shared__ float Ws[128 * 32];
    __shared__ float xs[32 * 128];
    int tid = threadIdx.x;
    int base = blockIdx.x * 32;
    for (int i = tid; i < 128 * 32; i += 256) Ws[i] = W[i];
    if (base + 32 <= n) {
        const float4* x4 = (const float4*)(x + (size_t)base * 128);
        for (int i = tid; i < 1024; i += 256) {
            float4 v = x4[i];
            xs[i * 4 + 0] = v.x; xs[i * 4 + 1] = v.y;
            xs[i * 4 + 2] = v.z; xs[i * 4 + 3] = v.w;
        }
    } else {
        for (int i = tid; i < 32 * 128; i += 256) {
            int r = i >> 7, c = i & 127;
            int row = base + r;
            xs[i] = (row < n) ? x[(size_t)row * 128 + c] : 0.f;
        }
    }
    __syncthreads();
    int r0 = tid >> 5, j = tid & 31;
    float a0 = 0.f, a1 = 0.f, a2 = 0.f, a3 = 0.f;
#pragma unroll 8
    for (int k = 0; k < 128; ++k) {
        float w = Ws[k * 32 + j];
        a0 = fmaf(xs[(r0     ) * 128 + k], w, a0);
        a1 = fmaf(xs[(r0 +  8) * 128 + k], w, a1);
        a2 = fmaf(xs[(r0 + 16) * 128 + k], w, a2);
        a3 = fmaf(xs[(r0 + 24) * 128 + k], w, a3);
    }
    int row;
    row = base + r0;      if (row < n) Y[(size_t)row * 32 + j] = __float2bfloat16(a0 * dinv[row]);
    row = base + r0 + 8;  if (row < n) Y[(size_t)row * 32 + j] = __float2bfloat16(a1 * dinv[row]);
    row = base + r0 + 16; if (row < n) Y[(size_t)row * 32 + j] = __float2bfloat16(a2 * dinv[row]);
    row = base + r0 + 24; if (row < n) Y[(size_t)row * 32 + j] = __float2bfloat16(a3 * dinv[row]);
}

__global__ __launch_bounds__(256) void k_gemm32(const float* __restrict__ H,
                                                const float* __restrict__ W,
                                                const float* __restrict__ scale,
                                                const float* __restrict__ shift,
                                                const float* __restrict__ dinv,
                                                bf16* __restrict__ Y, int n) {
    __shared__ float Ws[32 * 32];
    __shared__ float xs[32 * 32];
    int tid = threadIdx.x;
    int base = blockIdx.x * 32;
    for (int i = tid; i < 1024; i += 256) Ws[i] = W[i];
    for (int i = tid; i < 1024; i += 256) {
        int r = i >> 5, k = i & 31;
        int row = base + r;
        xs[i] = (row < n) ? fmaf(H[(size_t)row * 32 + k], scale[k], shift[k]) : 0.f;
    }
    __syncthreads();
    int r0 = tid >> 5, j = tid & 31;
    float a0 = 0.f, a1 = 0.f, a2 = 0.f, a3 = 0.f;
#pragma unroll
    for (int k = 0; k < 32; ++k) {
        float w = Ws[k * 32 + j];
        a0 = fmaf(xs[(r0     ) * 32 + k], w, a0);
        a1 = fmaf(xs[(r0 +  8) * 32 + k], w, a1);
        a2 = fmaf(xs[(r0 + 16) * 32 + k], w, a2);
        a3 = fmaf(xs[(r0 + 24) * 32 + k], w, a3);
    }
    int row;
    row = base + r0;      if (row < n) Y[(size_t)row * 32 + j] = __float2bfloat16(a0 * dinv[row]);
    row = base + r0 + 8;  if (row < n) Y[(size_t)row * 32 + j] = __float2bfloat16(a1 * dinv[row]);
    row = base + r0 + 16; if (row < n) Y[(size_t)row * 32 + j] = __float2bfloat16(a2 * dinv[row]);
    row = base + r0 + 24; if (row < n) Y[(size_t)row * 32 + j] = __float2bfloat16(a3 * dinv[row]);
}

// ======== atomic-free bucket-resident gather core (2-stage pipelined) ========
// Block b owns 392 rows; acc[392][32] f32 (padded 55 KB -> 2 blocks/CU),
// feature slot rotated by 4*(row&7). Wave w owns rows [49w,49w+49): no
// cross-wave sharing. Windows stride-transposed (S = ceil(cnt/16)); in-window
// dups only adjacent-quad, DPP suppress/absorb. SOFTWARE PIPELINE: at window
// w, issue cp[w+2]; DPP + Y-issue for w+1; absorb+RMW w with Y issued at w-1
// -> each global load gets a full iteration x4 waves before first use.
__device__ __forceinline__ void gather_acc(float* acc, const int* sw,
                                           const unsigned int* __restrict__ colP,
                                           const bf16* __restrict__ Y,
                                           int t, int NR) {
    int wv = t >> 6, lane = t & 63;
    int kq = lane >> 2, q = lane & 3, q8 = q * 8;
    for (int r = 0; r < NR; ++r) {
        int s0 = sw[r * 8 + wv];
        int cnt = sw[r * 8 + wv + 1] - s0;
        const unsigned int* cp = colP + s0;
        int S = (cnt + 15) >> 4;
        if (S > 0) {
            int base_li = (kq - 1 + q) * S;
            // lane-word fetch for window w (SENT when out of range)
            auto ldw = [&](int w) -> unsigned int {
                int li = w + base_li;
                return (w < S && li >= 0 && li < cnt) ? cp[li] : SENT;
            };
            // ---- prologue: window 0 state ----
            unsigned int wvdA = ldw(0);        // for window 0
            unsigned int wvdB = ldw(1);        // for window 1
            unsigned int myW   = (unsigned int)__builtin_amdgcn_mov_dpp((int)wvdA, 0x55, 0xF, 0xF, false);
            unsigned int prevW = (unsigned int)__builtin_amdgcn_mov_dpp((int)wvdA, 0x00, 0xF, 0xF, false);
            unsigned int nextW = (unsigned int)__builtin_amdgcn_mov_dpp((int)wvdA, 0xAA, 0xF, 0xF, false);
            bool val = (kq * S) < cnt;
            uint4 y = make_uint4(0u, 0u, 0u, 0u);
            if (val) y = *(const uint4*)(Y + (size_t)(myW & 0x3FFFFu) * 32 + q8);
            for (int w2 = 0; w2 < S; ++w2) {
                unsigned int wvdC = ldw(w2 + 2);            // stage-2 prefetch
                // stage-1: DPP + Y-issue for window w2+1
                unsigned int myW_n   = (unsigned int)__builtin_amdgcn_mov_dpp((int)wvdB, 0x55, 0xF, 0xF, false);
                unsigned int prevW_n = (unsigned int)__builtin_amdgcn_mov_dpp((int)wvdB, 0x00, 0xF, 0xF, false);
                unsigned int nextW_n = (unsigned int)__builtin_amdgcn_mov_dpp((int)wvdB, 0xAA, 0xF, 0xF, false);
                bool val_n = (w2 + 1 < S) && ((w2 + 1 + kq * S) < cnt);
                uint4 y_n = make_uint4(0u, 0u, 0u, 0u);
                if (val_n) y_n = *(const uint4*)(Y + (size_t)(myW_n & 0x3FFFFu) * 32 + q8);
                // stage-0: process window w2 (y was issued last iteration)
                int row = (int)(myW >> 18);
                bool sup = (prevW >> 18) == (myW >> 18);
                bool ab  = val && ((nextW >> 18) == (myW >> 18));
                float a0 = 0.f, a1 = 0.f, a2 = 0.f, a3 = 0.f;
                float a4 = 0.f, a5 = 0.f, a6 = 0.f, a7 = 0.f;
                if (val) {
                    a0 = lo16(y.x); a1 = hi16(y.x); a2 = lo16(y.y); a3 = hi16(y.y);
                    a4 = lo16(y.z); a5 = hi16(y.z); a6 = lo16(y.w); a7 = hi16(y.w);
                }
                if (__any(ab)) {                 // rare: absorb adjacent-quad dup
                    if (ab) {
                        int ns = (int)(nextW & 0x3FFFFu);
                        uint4 y2 = *(const uint4*)(Y + (size_t)ns * 32 + q8);
                        a0 += lo16(y2.x); a1 += hi16(y2.x); a2 += lo16(y2.y); a3 += hi16(y2.y);
                        a4 += lo16(y2.z); a5 += hi16(y2.z); a6 += lo16(y2.w); a7 += hi16(y2.w);
                    }
                }
                if (val && !sup) {
                    int rot = 4 * (row & 7);
                    float* A = acc + row * 32;
                    int f0 = (q8 + rot) & 31, f1 = (q8 + 4 + rot) & 31;
                    float4* P0 = (float4*)(A + f0);
                    float4* P1 = (float4*)(A + f1);
                    float4 u0 = *P0, u1 = *P1;
                    u0.x += a0; u0.y += a1; u0.z += a2; u0.w += a3;
                    u1.x += a4; u1.y += a5; u1.z += a6; u1.w += a7;
                    *P0 = u0; *P1 = u1;
                }
                // shift pipeline
                wvdB = wvdC;
                myW = myW_n; prevW = prevW_n; nextW = nextW_n;
                val = val_n; y = y_n;
            }
        }
        __syncthreads();   // range alignment within the block
    }
}

__device__ __forceinline__ void acc_init(float* acc, const bf16* __restrict__ Y,
                                         int bn0, int nn, int t) {
    for (int i = t; i < ROWSB * 4; i += 512) {
        int row = i >> 2, qq = (i & 3) * 8;
        uint4 v = make_uint4(0u, 0u, 0u, 0u);
        if (row < nn) v = *(const uint4*)(Y + (size_t)(bn0 + row) * 32 + qq);
        int rot = 4 * (row & 7);
        float* A = acc + row * 32;
        int f0 = (qq + rot) & 31, f1 = (qq + 4 + rot) & 31;
        A[f0 + 0] = lo16(v.x); A[f0 + 1] = hi16(v.x);
        A[f0 + 2] = lo16(v.y); A[f0 + 3] = hi16(v.y);
        A[f1 + 0] = lo16(v.z); A[f1 + 1] = hi16(v.z);
        A[f1 + 2] = lo16(v.w); A[f1 + 3] = hi16(v.w);
    }
}

// ======== gather + tanh + BN-stats (layers 1,2) ========
__global__ __launch_bounds__(512) void k_gather_bn(const int* __restrict__ segW,
                                                   const unsigned int* __restrict__ colP,
                                                   const bf16* __restrict__ Y,
                                                   const float* __restrict__ bias,
                                                   const float* __restrict__ dinv,
                                                   float* __restrict__ H,
                                                   float* __restrict__ stats,
                                                   int n, int NR) {
    __shared__ float acc[ACCPAD];            // 55 KB (padded: 2 blocks/CU exactly)
    __shared__ int sw[64];
    int b = blockIdx.x, t = threadIdx.x;
    int bn0 = b * ROWSB;
    int nn = n - bn0; if (nn > ROWSB) nn = ROWSB;
    if (t < 57) sw[t] = segW[b * 57 + t];
    acc_init(acc, Y, bn0, nn, t);
    __syncthreads();
    gather_acc(acc, sw, colP, Y, t, NR);
    // epilogue: feat-parallel
    int fr = t >> 5, f = t & 31;
    float bs = bias[f];
    float sA = 0.f, sQ = 0.f;
    for (int rr = fr; rr < nn; rr += 16) {
        float a = acc[rr * 32 + ((f + 4 * (rr & 7)) & 31)];
        float h = tanhf(fmaf(dinv[bn0 + rr], a, bs));
        H[(size_t)(bn0 + rr) * 32 + f] = h;
        sA += h; sQ += h * h;
    }
    __syncthreads();
    if (t < 64) acc[t] = 0.f;
    __syncthreads();
    ldsAdd(&acc[f], sA);
    ldsAdd(&acc[32 + f], sQ);
    __syncthreads();
    if (t < 64) atomAddF(&stats[t], acc[t]);
}

// ======== gather + tanh + mean-pool accumulate (layer 3) ========
__global__ __launch_bounds__(512) void k_gather_pool(const int* __restrict__ segW,
                                                     const unsigned int* __restrict__ colP,
                                                     const bf16* __restrict__ Y,
                                                     const float* __restrict__ bias,
                                                     const float* __restrict__ dinv,
                                                     const int* __restrict__ batch,
                                                     float* __restrict__ pool,
                                                     int n, int NR) {
    __shared__ float acc[ACCPAD];
    __shared__ int sw[64];
    int b = blockIdx.x, t = threadIdx.x;
    int bn0 = b * ROWSB;
    int nn = n - bn0; if (nn > ROWSB) nn = ROWSB;
    if (t < 57) sw[t] = segW[b * 57 + t];
    acc_init(acc, Y, bn0, nn, t);
    __syncthreads();
    gather_acc(acc, sw, colP, Y, t, NR);
    int fr = t >> 5, f = t & 31;
    float bs = bias[f];
    for (int rr = fr; rr < nn; rr += 16) {
        int row = bn0 + rr;
        float a = acc[rr * 32 + ((f + 4 * (rr & 7)) & 31)];
        float h = tanhf(fmaf(dinv[row], a, bs));
        atomAddF(&pool[(size_t)batch[row] * 32 + f], h);
    }
}

// ---- finalize BN -> per-feature affine (scale, shift) ----
__global__ void k_bnfin(const float* __restrict__ stats, const float* __restrict__ g,
                        const float* __restrict__ be, float* __restrict__ scale,
                        float* __restrict__ shift, float invN) {
    int f = threadIdx.x;  // 32 threads
    float mu = stats[f] * invN;
    float var = stats[32 + f] * invN - mu * mu;
    float inv = rsqrtf(var + EPSBN);
    float sc = g[f] * inv;
    scale[f] = sc;
    shift[f] = be[f] - mu * sc;
}

// ---- head: out[g] = (pool[g]/cnt[g]) @ Wc + bc ----
__global__ __launch_bounds__(256) void k_final(const float* __restrict__ pool,
                                               const int* __restrict__ cntg,
                                               const float* __restrict__ Wc,
                                               const float* __restrict__ bc,
                                               float* __restrict__ out, int G) {
    int g = blockIdx.x * 256 + threadIdx.x;
    if (g >= G) return;
    float inv = 1.f / (float)max(cntg[g], 1);
    float acc = bc[0];
#pragma unroll
    for (int f = 0; f < 32; ++f) acc = fmaf(pool[(size_t)g * 32 + f] * inv, Wc[f], acc);
    out[g] = acc;
}

extern "C" void kernel_launch(void* const* d_in, const int* in_sizes, int n_in,
                              void* d_out, int out_size, void* d_ws, size_t ws_size,
                              hipStream_t stream) {
    const float* x    = (const float*)d_in[0];
    const int*   ei   = (const int*)d_in[1];
    const int*   batch= (const int*)d_in[2];
    const float* W1   = (const float*)d_in[3];
    const float* b1   = (const float*)d_in[4];
    const float* g1   = (const float*)d_in[5];
    const float* be1  = (const float*)d_in[6];
    const float* W2   = (const float*)d_in[7];
    const float* b2   = (const float*)d_in[8];
    const float* g2   = (const float*)d_in[9];
    const float* be2  = (const float*)d_in[10];
    const float* W3   = (const float*)d_in[11];
    const float* b3   = (const float*)d_in[12];
    // d_in[13], d_in[14] = g3, be3 (unused by reference)
    const float* Wc   = (const float*)d_in[15];
    const float* bc   = (const float*)d_in[16];
    float* out = (float*)d_out;

    const int n = in_sizes[0] / 128;   // 200000
    const int E = in_sizes[1] / 2;     // 6400000
    const int G = out_size;            // 2048
    const int NB = (n + ROWSB - 1) / ROWSB;       // 511 buckets of 392 nodes
    const int NR = (n + (1 << RSH) - 1) >> RSH;   // 7 src ranges

    char* p = (char*)d_ws;
    auto alloc = [&p](size_t bytes) -> char* {
        uintptr_t q = ((uintptr_t)p + 255) & ~(uintptr_t)255;
        p = (char*)(q + bytes);
        return (char*)q;
    };
    // zero-initialized region first (contiguous from d_ws start)
    int*   cntg  = (int*)alloc((size_t)G * 4);
    float* stats = (float*)alloc(128 * 4);            // BN1: [0,64), BN2: [64,128)
    float* pool  = (float*)alloc((size_t)G * 32 * 4);
    int*   bcntP = (int*)alloc((size_t)NB * 4);       // padded reservations
    int*   bcntR = (int*)alloc((size_t)NB * 4);       // real counts
    size_t zero_bytes = (size_t)(p - (char*)d_ws);
    float* dinv   = (float*)alloc((size_t)n * 4);
    float* scale1 = (float*)alloc(32 * 4);
    float* shift1 = (float*)alloc(32 * 4);
    float* scale2 = (float*)alloc(32 * 4);
    float* shift2 = (float*)alloc(32 * 4);
    int*   bbase  = (int*)alloc((size_t)(NB + 1) * 4);
    int*   segW   = (int*)alloc((size_t)NB * 57 * 4);            // ~117 KB
    unsigned int* pairT = (unsigned int*)alloc((size_t)NB * BCAP * 4);  // ~43 MB
    unsigned int* colP  = (unsigned int*)alloc((size_t)E * 4);   // packed edges
    bf16*  bufY   = (bf16*)alloc((size_t)n * 32 * 2);
    float* bufH   = (float*)alloc((size_t)n * 32 * 4);

    hipMemsetAsync(d_ws, 0, zero_bytes, stream);

    int gN    = (n + 255) / 256;
    int gR32  = (n + 31) / 32;
    int gBuk  = (E + CHUNK - 1) / CHUNK;
    float invN = 1.0f / (float)n;

    // ---- build (range,row)-sorted bucketed edges (once; shared by 3 layers) ----
    k_cntg  <<<gN, 256, 0, stream>>>(batch, cntg, n);
    k_bucket<<<gBuk, 512, 0, stream>>>(ei, E, bcntP, bcntR, pairT, NB);
    k_bscan <<<1, 1024, 0, stream>>>(bcntR, bbase, NB);
    k_build <<<NB, 512, 0, stream>>>(pairT, bcntP, bbase, dinv, segW, colP, n, NR);

    // ---- layer 1 ----
    k_gemm1<<<gR32, 256, 0, stream>>>(x, W1, dinv, bufY, n);
    k_gather_bn<<<NB, 512, 0, stream>>>(segW, colP, bufY, b1, dinv, bufH, stats, n, NR);
    k_bnfin<<<1, 32, 0, stream>>>(stats, g1, be1, scale1, shift1, invN);

    // ---- layer 2 ----
    k_gemm32<<<gR32, 256, 0, stream>>>(bufH, W2, scale1, shift1, dinv, bufY, n);
    k_gather_bn<<<NB, 512, 0, stream>>>(segW, colP, bufY, b2, dinv, bufH, stats + 64, n, NR);
    k_bnfin<<<1, 32, 0, stream>>>(stats + 64, g2, be2, scale2, shift2, invN);

    // ---- layer 3 (tanh fused into pooling; no BN) ----
    k_gemm32<<<gR32, 256, 0, stream>>>(bufH, W3, scale2, shift2, dinv, bufY, n);
    k_gather_pool<<<NB, 512, 0, stream>>>(segW, colP, bufY, b3, dinv, batch, pool, n, NR);

    // ---- head ----
    k_final<<<(G + 255) / 256, 256, 0, stream>>>(pool, cntg, Wc, bc, out, G);
}